// Round 15
// baseline (214.519 us; speedup 1.0000x reference)
//
#include <hip/hip_runtime.h>

typedef __attribute__((ext_vector_type(8))) short short8;
typedef __attribute__((ext_vector_type(4))) float f32x4;
typedef __attribute__((ext_vector_type(16))) float f32x16;
typedef __attribute__((ext_vector_type(4))) unsigned short u16x4;
typedef __attribute__((ext_vector_type(4))) float float4v;

#define AS1 __attribute__((address_space(1)))
#define AS3 __attribute__((address_space(3)))

#define T_SEQ 2048
#define C_EMB 1024
#define NHEAD 16
#define NB    4
#define SCL_Q 0.18033688f   // 0.125 * log2(e)

__device__ __forceinline__ unsigned short f2bf(float f) {
    union { float f; unsigned u; } cv; cv.f = f;
    unsigned u = cv.u;
    unsigned r = (u + 0x7FFFu + ((u >> 16) & 1u)) >> 16;
    return (unsigned short)r;
}

__device__ __forceinline__ void async_load16(const void* g, void* l) {
    __builtin_amdgcn_global_load_lds((const AS1 unsigned*)g, (AS3 unsigned*)l, 16, 0, 0);
}

// permlane32_swap builtin (R12-proven): r[0] = {a.lo-lanes, b.lo-lanes}, r[1] = {a.hi, b.hi}
__device__ __forceinline__ void plswap_u(unsigned &a, unsigned &b) {
    auto r = __builtin_amdgcn_permlane32_swap(a, b, false, false);
    a = r[0]; b = r[1];
}
__device__ __forceinline__ float plswap_max(float t) {
    union { float f; unsigned u; } c; c.f = t;
    auto r = __builtin_amdgcn_permlane32_swap(c.u, c.u, false, false);
    union { unsigned u; float f; } x0, x1; x0.u = r[0]; x1.u = r[1];
    return fmaxf(x0.f, x1.f);
}
__device__ __forceinline__ float plswap_sum(float t) {
    union { float f; unsigned u; } c; c.f = t;
    auto r = __builtin_amdgcn_permlane32_swap(c.u, c.u, false, false);
    union { unsigned u; float f; } x0, x1; x0.u = r[0]; x1.u = r[1];
    return x0.f + x1.f;
}

// ---------------- fused f32 -> bf16 convert (x + 4 weights, one launch) ----------------
__global__ void cvt_all(const float* __restrict__ x,
                        const float* __restrict__ wq, const float* __restrict__ wk,
                        const float* __restrict__ wv, const float* __restrict__ wp,
                        unsigned short* __restrict__ xb,
                        unsigned short* __restrict__ wqkv,
                        unsigned short* __restrict__ wpb) {
    const int blk = blockIdx.x;
    const float* src; unsigned short* dst; int idx;
    if (blk < 8192) {
        src = x; dst = xb; idx = blk * 256 + threadIdx.x;
    } else {
        int wsel = (blk - 8192) >> 10;
        idx = ((blk - 8192) & 1023) * 256 + threadIdx.x;
        src = (wsel == 0) ? wq : (wsel == 1) ? wk : (wsel == 2) ? wv : wp;
        dst = (wsel == 3) ? wpb : wqkv + (size_t)wsel * 1048576;
    }
    float4v v = ((const float4v*)src)[idx];
    u16x4 o;
    o[0] = f2bf(v[0]); o[1] = f2bf(v[1]); o[2] = f2bf(v[2]); o[3] = f2bf(v[3]);
    ((u16x4*)dst)[idx] = o;
}

// ---------------- fused QKV GEMM: [8192,1024] x [3072,1024]^T ----------------
__global__ void gemm_qkv(const unsigned short* __restrict__ A,
                         const unsigned short* __restrict__ W,
                         const float* __restrict__ bq,
                         const float* __restrict__ bk,
                         const float* __restrict__ bv,
                         unsigned short* __restrict__ Qo,
                         unsigned short* __restrict__ Ko,
                         unsigned short* __restrict__ Vt) {
    __shared__ __align__(16) unsigned short As[128 * 32];
    __shared__ __align__(16) unsigned short Bs[128 * 32];
    const int tid  = threadIdx.x;
    const int wid  = tid >> 6;
    const int lane = tid & 63;
    const int lg = lane >> 4, lr = lane & 15;
    const int wr = wid >> 1, wc = wid & 1;
    const int n0 = blockIdx.x * 128;
    const int m0 = blockIdx.y * 128;
    const int K = 1024;

    f32x4 acc[4][4] = {};

    for (int kt = 0; kt < K; kt += 32) {
        #pragma unroll
        for (int r = 0; r < 2; ++r) {
            int cb = r * 4 + wid;
            int chunk = cb * 64 + lane;
            int row = chunk >> 2;
            int col = (chunk & 3) * 8;
            async_load16(&A[(size_t)(m0 + row) * K + kt + col], (char*)As + cb * 1024);
            async_load16(&W[(size_t)(n0 + row) * K + kt + col], (char*)Bs + cb * 1024);
        }
        __syncthreads();
        short8 af[4], bfr[4];
        #pragma unroll
        for (int m = 0; m < 4; ++m)
            af[m] = *(const short8*)&As[(wr * 64 + m * 16 + lr) * 32 + lg * 8];
        #pragma unroll
        for (int n = 0; n < 4; ++n)
            bfr[n] = *(const short8*)&Bs[(wc * 64 + n * 16 + lr) * 32 + lg * 8];
        #pragma unroll
        for (int m = 0; m < 4; ++m)
            #pragma unroll
            for (int n = 0; n < 4; ++n)
                acc[m][n] = __builtin_amdgcn_mfma_f32_16x16x32_bf16(af[m], bfr[n], acc[m][n], 0, 0, 0);
        __syncthreads();
    }

    const int sel = n0 >> 10;
    const int nl0 = n0 & 1023;
    const float* bias = (sel == 0) ? bq : (sel == 1) ? bk : bv;
    const float scale = (sel == 0) ? SCL_Q : 1.0f;

    #pragma unroll
    for (int n = 0; n < 4; ++n) {
        int cc = nl0 + wc * 64 + n * 16 + lr;
        float bvv = bias[cc];
        #pragma unroll
        for (int m = 0; m < 4; ++m) {
            int rr0 = m0 + wr * 64 + m * 16 + lg * 4;
            u16x4 pk;
            #pragma unroll
            for (int r = 0; r < 4; ++r)
                pk[r] = f2bf((acc[m][n][r] + bvv) * scale);
            if (sel == 2) {
                size_t idx = ((size_t)(rr0 >> 11) * 1024 + cc) * 2048 + (rr0 & 2047);
                *(u16x4*)&Vt[idx] = pk;
            } else {
                unsigned short* out = (sel == 0) ? Qo : Ko;
                #pragma unroll
                for (int r = 0; r < 4; ++r)
                    out[(size_t)(rr0 + r) * 1024 + cc] = pk[r];
            }
        }
    }
}

// ---------------- proj GEMM: C[M,N] = A[M,K]*B[N,K]^T + bias (f32 out) ----------------
__global__ void gemm_proj(const unsigned short* __restrict__ A,
                          const unsigned short* __restrict__ B,
                          const float* __restrict__ bias,
                          float* __restrict__ Cout,
                          int M, int N, int K) {
    __shared__ __align__(16) unsigned short As[128 * 32];
    __shared__ __align__(16) unsigned short Bs[128 * 32];
    const int tid  = threadIdx.x;
    const int wid  = tid >> 6;
    const int lane = tid & 63;
    const int lg = lane >> 4, lr = lane & 15;
    const int wr = wid >> 1, wc = wid & 1;
    const int n0 = blockIdx.x * 128;
    const int m0 = blockIdx.y * 128;

    f32x4 acc[4][4] = {};

    for (int kt = 0; kt < K; kt += 32) {
        #pragma unroll
        for (int r = 0; r < 2; ++r) {
            int cb = r * 4 + wid;
            int chunk = cb * 64 + lane;
            int row = chunk >> 2;
            int col = (chunk & 3) * 8;
            async_load16(&A[(size_t)(m0 + row) * K + kt + col], (char*)As + cb * 1024);
            async_load16(&B[(size_t)(n0 + row) * K + kt + col], (char*)Bs + cb * 1024);
        }
        __syncthreads();
        short8 af[4], bfr[4];
        #pragma unroll
        for (int m = 0; m < 4; ++m)
            af[m] = *(const short8*)&As[(wr * 64 + m * 16 + lr) * 32 + lg * 8];
        #pragma unroll
        for (int n = 0; n < 4; ++n)
            bfr[n] = *(const short8*)&Bs[(wc * 64 + n * 16 + lr) * 32 + lg * 8];
        #pragma unroll
        for (int m = 0; m < 4; ++m)
            #pragma unroll
            for (int n = 0; n < 4; ++n)
                acc[m][n] = __builtin_amdgcn_mfma_f32_16x16x32_bf16(af[m], bfr[n], acc[m][n], 0, 0, 0);
        __syncthreads();
    }

    #pragma unroll
    for (int n = 0; n < 4; ++n) {
        int cc = n0 + wc * 64 + n * 16 + lr;
        float bvv = bias[cc];
        #pragma unroll
        for (int m = 0; m < 4; ++m) {
            int rr0 = m0 + wr * 64 + m * 16 + lg * 4;
            #pragma unroll
            for (int r = 0; r < 4; ++r)
                Cout[(size_t)(rr0 + r) * N + cc] = acc[m][n][r] + bvv;
        }
    }
}

// ---------------- flash attention part 1: split-K x2, partial (O,m,l) ----------------
// R14's proven 4-wave/32x32 body; each block computes HALF the K-range of its
// (bh, 128-row q-group): kh=0 -> tiles [0,g+1), kh=1 -> [g+1,2g+2) -- uniform
// g+1 tiles per block. Grid 2048 = 8 blocks/CU submitted vs ~6 resident -> the
// CU scheduler finally has refill. Raw O (f32) + m,l written to workspace;
// normalization happens in attn_merge.
__global__ __launch_bounds__(256, 2) void attn_part(const unsigned short* __restrict__ Q,
                                                    const unsigned short* __restrict__ Kg,
                                                    const unsigned short* __restrict__ Vt,
                                                    float* __restrict__ pbuf,
                                                    float* __restrict__ mlb) {
    __shared__ __align__(16) unsigned short Ks[2][64 * 64];   // 2 x 8KB, swizzled

    const int bid = blockIdx.x;            // 0..2047
    const int xcd = bid & 7;
    const int s   = bid >> 3;              // 0..255
    const int kh  = s & 1;                 // K-half
    const int s2  = s >> 1;                // 0..127
    const int grp = 15 - (s2 >> 3);        // 15..0 (longest-job-first)
    const int bh  = (s2 & 7) * 8 + xcd;    // 0..63, pinned to this XCD
    const int h   = bh & 15;
    const int b   = bh >> 4;

    const int tid  = threadIdx.x;
    const int w    = tid >> 6;
    const int lane = tid & 63;
    const int ql = lane & 31, hi = lane >> 5;

    const size_t rowbase = ((size_t)b * T_SEQ) * C_EMB + (size_t)h * 64;   // Q,K
    const size_t vtbase  = ((size_t)b * 1024 + (size_t)h * 64) * T_SEQ;    // Vt [d][t]

    const int srow = lane >> 3;
    const int scol = ((lane & 7) ^ srow) * 8;

    const int q0  = grp * 128;
    const int qw0 = q0 + w * 32;
    const int t0  = kh ? (grp + 1) : 0;    // this block's K-tile range start
    const int ntl = grp + 1;               // local tile count (uniform in grp)

    // Q B-frags: lane holds Q[qw0+ql][ds*16 + hi*8 .. +8)
    short8 qf[4];
    #pragma unroll
    for (int ds = 0; ds < 4; ++ds)
        qf[ds] = *(const short8*)&Q[rowbase + (size_t)(qw0 + ql) * C_EMB + ds * 16 + hi * 8];

    f32x16 o0 = {}, o1 = {};
    float mrun = -1e30f, lsum = 0.0f;

    // prologue: stage K tile t0 -> buf 0
    #pragma unroll
    for (int i = 0; i < 2; ++i) {
        int cb = w * 2 + i;
        async_load16(&Kg[rowbase + (size_t)(t0 * 64 + cb * 8 + srow) * C_EMB + scol],
                     (char*)Ks[0] + cb * 1024);
    }

    #pragma unroll 1
    for (int tl = 0; tl < ntl; ++tl) {
        const int kv0 = (t0 + tl) * 64;
        const int cur = tl & 1, nxt = cur ^ 1;
        __syncthreads();   // K tile ready; buf[nxt] free

        const bool active = (kv0 <= qw0 + 31);

        // V prefetch to regs
        short8 vf0[4], vf1[4];
        if (active) {
            #pragma unroll
            for (int ks = 0; ks < 4; ++ks) {
                vf0[ks] = *(const short8*)&Vt[vtbase + (size_t)ql * T_SEQ + kv0 + ks * 16 + hi * 8];
                vf1[ks] = *(const short8*)&Vt[vtbase + (size_t)(32 + ql) * T_SEQ + kv0 + ks * 16 + hi * 8];
            }
        }
        // stage next K tile
        if (tl + 1 < ntl) {
            #pragma unroll
            for (int i = 0; i < 2; ++i) {
                int cb = w * 2 + i;
                async_load16(&Kg[rowbase + (size_t)(kv0 + 64 + cb * 8 + srow) * C_EMB + scol],
                             (char*)Ks[nxt] + cb * 1024);
            }
        }
        if (!active) continue;

        // ---- S^T = K * Q^T ----
        f32x16 sa0 = {}, sa1 = {};
        __builtin_amdgcn_s_setprio(1);
        #pragma unroll
        for (int ds = 0; ds < 4; ++ds) {
            short8 a0 = *(const short8*)((const char*)Ks[cur] + (ql) * 128 +
                                         ((ds * 32 + hi * 16) ^ ((ql & 7) << 4)));
            short8 a1 = *(const short8*)((const char*)Ks[cur] + (32 + ql) * 128 +
                                         ((ds * 32 + hi * 16) ^ ((ql & 7) << 4)));
            sa0 = __builtin_amdgcn_mfma_f32_32x32x16_bf16(a0, qf[ds], sa0, 0, 0, 0);
            sa1 = __builtin_amdgcn_mfma_f32_32x32x16_bf16(a1, qf[ds], sa1, 0, 0, 0);
        }
        __builtin_amdgcn_s_setprio(0);

        // ---- causal mask ----
        if (kv0 + 63 > qw0) {
            const int qi = qw0 + ql;
            #pragma unroll
            for (int r = 0; r < 16; ++r) {
                int kl = (r & 3) + 8 * (r >> 2) + 4 * hi;
                if (kv0 + kl > qi)      sa0[r] = -1e30f;
                if (kv0 + 32 + kl > qi) sa1[r] = -1e30f;
            }
        }

        // ---- lane-local online softmax, exp2 domain ----
        float mx[8];
        #pragma unroll
        for (int r = 0; r < 8; ++r)
            mx[r] = fmaxf(fmaxf(sa0[r], sa0[r + 8]), fmaxf(sa1[r], sa1[r + 8]));
        mx[0] = fmaxf(mx[0], mx[4]); mx[1] = fmaxf(mx[1], mx[5]);
        mx[2] = fmaxf(mx[2], mx[6]); mx[3] = fmaxf(mx[3], mx[7]);
        float tmax = fmaxf(fmaxf(mx[0], mx[1]), fmaxf(mx[2], mx[3]));
        tmax = plswap_max(tmax);
        if (!__all(tmax <= mrun + 8.0f)) {
            float mn  = fmaxf(mrun, tmax);
            float scl = exp2f(mrun - mn);
            mrun = mn;
            lsum *= scl;
            #pragma unroll
            for (int gg = 0; gg < 4; ++gg)
                #pragma unroll
                for (int r2 = 0; r2 < 4; ++r2) {
                    float sc = __shfl(scl, gg * 8 + 4 * hi + r2);
                    o0[gg * 4 + r2] *= sc;
                    o1[gg * 4 + r2] *= sc;
                }
        }
        #pragma unroll
        for (int r = 0; r < 16; ++r) {
            sa0[r] = exp2f(sa0[r] - mrun);
            sa1[r] = exp2f(sa1[r] - mrun);
        }
        float sm[8];
        #pragma unroll
        for (int r = 0; r < 8; ++r)
            sm[r] = (sa0[r] + sa0[r + 8]) + (sa1[r] + sa1[r + 8]);
        lsum += ((sm[0] + sm[1]) + (sm[2] + sm[3])) + ((sm[4] + sm[5]) + (sm[6] + sm[7]));

        // ---- P -> bf16 packed words ----
        unsigned pw0[8], pw1[8];
        #pragma unroll
        for (int gg = 0; gg < 4; ++gg)
            #pragma unroll
            for (int hh = 0; hh < 2; ++hh) {
                asm("v_cvt_pk_bf16_f32 %0, %1, %2"
                    : "=v"(pw0[gg * 2 + hh]) : "v"(sa0[4 * gg + 2 * hh]), "v"(sa0[4 * gg + 2 * hh + 1]));
                asm("v_cvt_pk_bf16_f32 %0, %1, %2"
                    : "=v"(pw1[gg * 2 + hh]) : "v"(sa1[4 * gg + 2 * hh]), "v"(sa1[4 * gg + 2 * hh + 1]));
            }

        // ---- in-register P redistribution via permlane32_swap ----
        short8 pf[4];
        #pragma unroll
        for (int ks = 0; ks < 4; ++ks) {
            const int g0 = (2 * ks) & 3, g1 = (2 * ks + 1) & 3;
            unsigned p0, q0c, p1, q1c;
            if (ks < 2) { p0 = pw0[g0 * 2]; p1 = pw0[g0 * 2 + 1];
                          q0c = pw0[g1 * 2]; q1c = pw0[g1 * 2 + 1]; }
            else        { p0 = pw1[g0 * 2]; p1 = pw1[g0 * 2 + 1];
                          q0c = pw1[g1 * 2]; q1c = pw1[g1 * 2 + 1]; }
            plswap_u(p0, q0c);
            plswap_u(p1, q1c);
            union { unsigned u[4]; short8 v; } uu;
            uu.u[0] = p0;
            uu.u[1] = p1;
            uu.u[2] = q0c;
            uu.u[3] = q1c;
            pf[ks] = uu.v;
        }

        // ---- PV ----
        __builtin_amdgcn_s_setprio(1);
        #pragma unroll
        for (int ks = 0; ks < 4; ++ks) {
            o0 = __builtin_amdgcn_mfma_f32_32x32x16_bf16(pf[ks], vf0[ks], o0, 0, 0, 0);
            o1 = __builtin_amdgcn_mfma_f32_32x32x16_bf16(pf[ks], vf1[ks], o1, 0, 0, 0);
        }
        __builtin_amdgcn_s_setprio(0);
    }

    // ---- epilogue: write RAW partial O + (m, l) to workspace (no normalize) ----
    float lw = plswap_sum(lsum);
    const size_t pidx = ((size_t)(bh * 16 + grp) * 2 + kh);
    float* pb = pbuf + pidx * 8192 + (size_t)w * 32 * 64;   // this wave's 32 rows
    #pragma unroll
    for (int gg = 0; gg < 4; ++gg)
        #pragma unroll
        for (int r2 = 0; r2 < 4; ++r2) {
            int row = gg * 8 + 4 * hi + r2;
            pb[row * 64 + ql]      = o0[gg * 4 + r2];
            pb[row * 64 + 32 + ql] = o1[gg * 4 + r2];
        }
    if (hi == 0) {
        mlb[pidx * 256 + w * 32 + ql]       = mrun;
        mlb[pidx * 256 + 128 + w * 32 + ql] = lw;
    }
}

// ---------------- flash attention part 2: merge the two K-halves ----------------
__global__ void attn_merge(const float* __restrict__ pbuf, const float* __restrict__ mlb,
                           unsigned short* __restrict__ Y) {
    const int mblk = blockIdx.x;           // 0..1023 = bh*16 + grp
    const int bh = mblk >> 4, grp = mblk & 15;
    const int b = bh >> 4, h = bh & 15;
    const int tid = threadIdx.x;
    const int r  = tid >> 1;               // row 0..127
    const int c0 = (tid & 1) * 32;         // col half

    const size_t base = (size_t)(bh * 16 + grp) * 2;
    const size_t p0 = (base + 0) * 8192;
    const size_t p1 = (base + 1) * 8192;
    const size_t m0i = (base + 0) * 256;
    const size_t m1i = (base + 1) * 256;

    float m0 = mlb[m0i + r], l0 = mlb[m0i + 128 + r];
    float m1 = mlb[m1i + r], l1 = mlb[m1i + 128 + r];
    float M  = fmaxf(m0, m1);
    float f0 = exp2f(m0 - M), f1 = exp2f(m1 - M);
    float inv = 1.0f / (f0 * l0 + f1 * l1);
    f0 *= inv; f1 *= inv;

    const int q = grp * 128 + r;
    unsigned short* yp = Y + ((size_t)b * T_SEQ + q) * C_EMB + (size_t)h * 64 + c0;
    const float* pa = pbuf + p0 + (size_t)r * 64 + c0;
    const float* pbb = pbuf + p1 + (size_t)r * 64 + c0;

    #pragma unroll
    for (int i = 0; i < 8; ++i) {
        float4v va = *(const float4v*)(pa + i * 4);
        float4v vb = *(const float4v*)(pbb + i * 4);
        u16x4 o;
        #pragma unroll
        for (int j = 0; j < 4; ++j)
            o[j] = f2bf(f0 * va[j] + f1 * vb[j]);
        *(u16x4*)(yp + i * 4) = o;
    }
}

// ---------------- launcher ----------------
extern "C" void kernel_launch(void* const* d_in, const int* in_sizes, int n_in,
                              void* d_out, int out_size, void* d_ws, size_t ws_size,
                              hipStream_t stream) {
    const float* x  = (const float*)d_in[0];
    const float* Wk = (const float*)d_in[1];
    const float* bk = (const float*)d_in[2];
    const float* Wq = (const float*)d_in[3];
    const float* bq = (const float*)d_in[4];
    const float* Wv = (const float*)d_in[5];
    const float* bv = (const float*)d_in[6];
    const float* Wp = (const float*)d_in[7];
    const float* bp = (const float*)d_in[8];

    const size_t SX = (size_t)8192 * 1024;
    const size_t SW = (size_t)1024 * 1024;

    char* ws = (char*)d_ws;
    unsigned short* xb   = (unsigned short*)ws; ws += SX * 2;
    unsigned short* Wqkv = (unsigned short*)ws; ws += 3 * SW * 2;  // [Wq;Wk;Wv] rows
    unsigned short* Wpb  = (unsigned short*)ws; ws += SW * 2;
    unsigned short* qb   = (unsigned short*)ws; ws += SX * 2;
    unsigned short* kb   = (unsigned short*)ws; ws += SX * 2;
    unsigned short* vtb  = (unsigned short*)ws; ws += SX * 2;  // V^T per head [b][h][d][t]
    unsigned short* yb   = (unsigned short*)ws; ws += SX * 2;
    float* pbuf          = (float*)ws;          ws += (size_t)2048 * 8192 * 4;  // 64 MB partials
    float* mlb           = (float*)ws;          ws += (size_t)2048 * 256 * 4;   // 2 MB m/l

    cvt_all<<<dim3(12288), 256, 0, stream>>>(x, Wq, Wk, Wv, Wp, xb, Wqkv, Wpb);

    gemm_qkv<<<dim3(24, 64), 256, 0, stream>>>(xb, Wqkv, bq, bk, bv, qb, kb, vtb);

    attn_part<<<dim3(2048), 256, 0, stream>>>(qb, kb, vtb, pbuf, mlb);
    attn_merge<<<dim3(1024), 256, 0, stream>>>(pbuf, mlb, yb);

    gemm_proj<<<dim3(8, 64), 256, 0, stream>>>(yb, Wpb, bp, (float*)d_out, 8192, 1024, 1024);
}

// Round 16
// 204.479 us; speedup vs baseline: 1.0491x; 1.0491x over previous
//
#include <hip/hip_runtime.h>

typedef __attribute__((ext_vector_type(8))) short short8;
typedef __attribute__((ext_vector_type(4))) float f32x4;
typedef __attribute__((ext_vector_type(16))) float f32x16;
typedef __attribute__((ext_vector_type(4))) unsigned short u16x4;
typedef __attribute__((ext_vector_type(4))) float float4v;

#define AS1 __attribute__((address_space(1)))
#define AS3 __attribute__((address_space(3)))

#define T_SEQ 2048
#define C_EMB 1024
#define NHEAD 16
#define NB    4
#define SCL_Q 0.18033688f   // 0.125 * log2(e)

__device__ __forceinline__ unsigned short f2bf(float f) {
    union { float f; unsigned u; } cv; cv.f = f;
    unsigned u = cv.u;
    unsigned r = (u + 0x7FFFu + ((u >> 16) & 1u)) >> 16;
    return (unsigned short)r;
}

__device__ __forceinline__ void async_load16(const void* g, void* l) {
    __builtin_amdgcn_global_load_lds((const AS1 unsigned*)g, (AS3 unsigned*)l, 16, 0, 0);
}

// permlane32_swap builtin (R12-proven)
__device__ __forceinline__ void plswap_u(unsigned &a, unsigned &b) {
    auto r = __builtin_amdgcn_permlane32_swap(a, b, false, false);
    a = r[0]; b = r[1];
}
__device__ __forceinline__ float plswap_max(float t) {
    union { float f; unsigned u; } c; c.f = t;
    auto r = __builtin_amdgcn_permlane32_swap(c.u, c.u, false, false);
    union { unsigned u; float f; } x0, x1; x0.u = r[0]; x1.u = r[1];
    return fmaxf(x0.f, x1.f);
}
__device__ __forceinline__ float plswap_sum(float t) {
    union { float f; unsigned u; } c; c.f = t;
    auto r = __builtin_amdgcn_permlane32_swap(c.u, c.u, false, false);
    union { unsigned u; float f; } x0, x1; x0.u = r[0]; x1.u = r[1];
    return x0.f + x1.f;
}

// ---------------- fused f32 -> bf16 convert ----------------
__global__ void cvt_all(const float* __restrict__ x,
                        const float* __restrict__ wq, const float* __restrict__ wk,
                        const float* __restrict__ wv, const float* __restrict__ wp,
                        unsigned short* __restrict__ xb,
                        unsigned short* __restrict__ wqkv,
                        unsigned short* __restrict__ wpb) {
    const int blk = blockIdx.x;
    const float* src; unsigned short* dst; int idx;
    if (blk < 8192) {
        src = x; dst = xb; idx = blk * 256 + threadIdx.x;
    } else {
        int wsel = (blk - 8192) >> 10;
        idx = ((blk - 8192) & 1023) * 256 + threadIdx.x;
        src = (wsel == 0) ? wq : (wsel == 1) ? wk : (wsel == 2) ? wv : wp;
        dst = (wsel == 3) ? wpb : wqkv + (size_t)wsel * 1048576;
    }
    float4v v = ((const float4v*)src)[idx];
    u16x4 o;
    o[0] = f2bf(v[0]); o[1] = f2bf(v[1]); o[2] = f2bf(v[2]); o[3] = f2bf(v[3]);
    ((u16x4*)dst)[idx] = o;
}

// ---------------- QKV GEMM, 256x256 8-phase schedule (T3+T4) ----------------
// [8192,1024] x [3072,1024]^T. BM=BN=256, BK=64, 8 waves (2Mx4N), per-wave 128x64.
// LDS 128KB: 2 dbuf x (A 32KB + B 32KB), granule-XOR swizzle (both-sides, rule 21).
// Per K-tile: 4 quadrant-phases {ds_read frags || 2 stage-loads -> s_barrier ->
// lgkmcnt(0)+sched_barrier -> setprio(1) 16 MFMA setprio(0) -> s_barrier};
// vmcnt(0)+barrier once per K-tile (stage loads issued 2/phase get >=3 phases cover).
__global__ __launch_bounds__(512, 2) void gemm_qkv8(const unsigned short* __restrict__ A,
                                                    const unsigned short* __restrict__ W,
                                                    const float* __restrict__ bq,
                                                    const float* __restrict__ bk,
                                                    const float* __restrict__ bv,
                                                    unsigned short* __restrict__ Qo,
                                                    unsigned short* __restrict__ Ko,
                                                    unsigned short* __restrict__ Vt) {
    __shared__ __align__(16) unsigned short Abuf[2][256 * 64];   // 2 x 32KB
    __shared__ __align__(16) unsigned short Bbuf[2][256 * 64];   // 2 x 32KB

    const int tid  = threadIdx.x;
    const int wid  = tid >> 6;
    const int lane = tid & 63;
    const int lr = lane & 15, lg = lane >> 4;
    const int wr = wid >> 2, wc = wid & 3;        // 2M x 4N wave grid
    const int n0 = blockIdx.x * 256;
    const int m0 = blockIdx.y * 256;
    const int K  = 1024;

    // staging geometry (both-sides swizzle): thread stages row j*64+(tid>>3),
    // LDS dest linear (wave-uniform base + lane*16); global granule pre-swizzled.
    const int srow = tid >> 3;                    // 0..63 within 64-row chunk
    const int sgE  = ((tid & 7) ^ (srow & 7)) * 8; // global col elems (granule^row&7)

    f32x4 acc[8][4] = {};

    // prologue: stage K-tile 0 into buf 0 (A: 4 chunks, B: 4 chunks)
    #pragma unroll
    for (int j = 0; j < 4; ++j) {
        async_load16(&A[(size_t)(m0 + j * 64 + srow) * K + sgE],
                     (char*)Abuf[0] + j * 8192 + tid * 16);
        async_load16(&W[(size_t)(n0 + j * 64 + srow) * K + sgE],
                     (char*)Bbuf[0] + j * 8192 + tid * 16);
    }
    asm volatile("s_waitcnt vmcnt(0)" ::: "memory");
    __builtin_amdgcn_s_barrier();

    #pragma unroll 1
    for (int t = 0; t < 16; ++t) {
        const int cur = t & 1, nxt = cur ^ 1;
        const unsigned short* Ac = Abuf[cur];
        const unsigned short* Bc = Bbuf[cur];

        #pragma unroll
        for (int q = 0; q < 4; ++q) {             // quadrant phase: mh=q>>1, nh=q&1
            const int mh = q >> 1, nh = q & 1;

            // ---- ds_read this quadrant's fragments ----
            short8 af[4][2], bf[2][2];
            #pragma unroll
            for (int mi = 0; mi < 4; ++mi) {
                int row = wr * 128 + (mh * 4 + mi) * 16 + lr;
                #pragma unroll
                for (int ks = 0; ks < 2; ++ks)
                    af[mi][ks] = *(const short8*)((const char*)Ac + row * 128 +
                                                  ((ks * 64 + lg * 16) ^ ((lr & 7) << 4)));
            }
            #pragma unroll
            for (int ni = 0; ni < 2; ++ni) {
                int brow = wc * 64 + (nh * 2 + ni) * 16 + lr;
                #pragma unroll
                for (int ks = 0; ks < 2; ++ks)
                    bf[ni][ks] = *(const short8*)((const char*)Bc + brow * 128 +
                                                  ((ks * 64 + lg * 16) ^ ((lr & 7) << 4)));
            }
            // ---- issue next-tile stage chunk q (2 loads) ----
            if (t + 1 < 16) {
                async_load16(&A[(size_t)(m0 + q * 64 + srow) * K + (t + 1) * 64 + sgE],
                             (char*)Abuf[nxt] + q * 8192 + tid * 16);
                async_load16(&W[(size_t)(n0 + q * 64 + srow) * K + (t + 1) * 64 + sgE],
                             (char*)Bbuf[nxt] + q * 8192 + tid * 16);
            }
            __builtin_amdgcn_s_barrier();
            asm volatile("s_waitcnt lgkmcnt(0)" ::: "memory");
            __builtin_amdgcn_sched_barrier(0);    // rule 18: pin MFMA after the wait
            __builtin_amdgcn_s_setprio(1);
            #pragma unroll
            for (int ks = 0; ks < 2; ++ks)
                #pragma unroll
                for (int mi = 0; mi < 4; ++mi)
                    #pragma unroll
                    for (int ni = 0; ni < 2; ++ni)
                        acc[mh * 4 + mi][nh * 2 + ni] =
                            __builtin_amdgcn_mfma_f32_16x16x32_bf16(
                                af[mi][ks], bf[ni][ks], acc[mh * 4 + mi][nh * 2 + ni], 0, 0, 0);
            __builtin_amdgcn_s_setprio(0);
            __builtin_amdgcn_s_barrier();
        }
        // iter end: next tile's 8 loads must have landed before next phase-0 ds_read
        asm volatile("s_waitcnt vmcnt(0)" ::: "memory");
        __builtin_amdgcn_s_barrier();
    }

    // ---- epilogue ----
    const int sel = n0 >> 10;                     // 0=Q 1=K 2=V (256 | 1024)
    const int nl0 = n0 & 1023;
    const float* bias = (sel == 0) ? bq : (sel == 1) ? bk : bv;
    const float scale = (sel == 0) ? SCL_Q : 1.0f;

    #pragma unroll
    for (int nf = 0; nf < 4; ++nf) {
        int cc = nl0 + wc * 64 + nf * 16 + lr;
        float bvv = bias[cc];
        #pragma unroll
        for (int mf = 0; mf < 8; ++mf) {
            int rr0 = m0 + wr * 128 + mf * 16 + lg * 4;
            u16x4 pk;
            #pragma unroll
            for (int r = 0; r < 4; ++r)
                pk[r] = f2bf((acc[mf][nf][r] + bvv) * scale);
            if (sel == 2) {
                size_t idx = ((size_t)(rr0 >> 11) * 1024 + cc) * 2048 + (rr0 & 2047);
                *(u16x4*)&Vt[idx] = pk;
            } else {
                unsigned short* out = (sel == 0) ? Qo : Ko;
                #pragma unroll
                for (int r = 0; r < 4; ++r)
                    out[(size_t)(rr0 + r) * 1024 + cc] = pk[r];
            }
        }
    }
}

// ---------------- proj GEMM: C[M,N] = A[M,K]*B[N,K]^T + bias (f32 out, 128-tile) ----------------
__global__ void gemm_proj(const unsigned short* __restrict__ A,
                          const unsigned short* __restrict__ B,
                          const float* __restrict__ bias,
                          float* __restrict__ Cout,
                          int M, int N, int K) {
    __shared__ __align__(16) unsigned short As[128 * 32];
    __shared__ __align__(16) unsigned short Bs[128 * 32];
    const int tid  = threadIdx.x;
    const int wid  = tid >> 6;
    const int lane = tid & 63;
    const int lg = lane >> 4, lr = lane & 15;
    const int wr = wid >> 1, wc = wid & 1;
    const int n0 = blockIdx.x * 128;
    const int m0 = blockIdx.y * 128;

    f32x4 acc[4][4] = {};

    for (int kt = 0; kt < K; kt += 32) {
        #pragma unroll
        for (int r = 0; r < 2; ++r) {
            int cb = r * 4 + wid;
            int chunk = cb * 64 + lane;
            int row = chunk >> 2;
            int col = (chunk & 3) * 8;
            async_load16(&A[(size_t)(m0 + row) * K + kt + col], (char*)As + cb * 1024);
            async_load16(&B[(size_t)(n0 + row) * K + kt + col], (char*)Bs + cb * 1024);
        }
        __syncthreads();
        short8 af[4], bfr[4];
        #pragma unroll
        for (int m = 0; m < 4; ++m)
            af[m] = *(const short8*)&As[(wr * 64 + m * 16 + lr) * 32 + lg * 8];
        #pragma unroll
        for (int n = 0; n < 4; ++n)
            bfr[n] = *(const short8*)&Bs[(wc * 64 + n * 16 + lr) * 32 + lg * 8];
        #pragma unroll
        for (int m = 0; m < 4; ++m)
            #pragma unroll
            for (int n = 0; n < 4; ++n)
                acc[m][n] = __builtin_amdgcn_mfma_f32_16x16x32_bf16(af[m], bfr[n], acc[m][n], 0, 0, 0);
        __syncthreads();
    }

    #pragma unroll
    for (int n = 0; n < 4; ++n) {
        int cc = n0 + wc * 64 + n * 16 + lr;
        float bvv = bias[cc];
        #pragma unroll
        for (int m = 0; m < 4; ++m) {
            int rr0 = m0 + wr * 64 + m * 16 + lg * 4;
            #pragma unroll
            for (int r = 0; r < 4; ++r)
                Cout[(size_t)(rr0 + r) * N + cc] = acc[m][n][r] + bvv;
        }
    }
}

// ---------------- flash attention (R14-proven: 4-wave 32x32, 90us) ----------------
__global__ __launch_bounds__(256, 2) void attn_fwd16(const unsigned short* __restrict__ Q,
                                                     const unsigned short* __restrict__ Kg,
                                                     const unsigned short* __restrict__ Vt,
                                                     unsigned short* __restrict__ Y) {
    __shared__ __align__(16) unsigned short Ks[2][64 * 64];   // 2 x 8KB, swizzled

    const int bid = blockIdx.x;            // 0..1023
    const int xcd = bid & 7;
    const int s   = bid >> 3;              // 0..127
    const int grp = 15 - (s >> 3);         // 15..0 (longest-job-first)
    const int bh  = (s & 7) * 8 + xcd;     // 0..63, pinned to this XCD
    const int h   = bh & 15;
    const int b   = bh >> 4;

    const int tid  = threadIdx.x;
    const int w    = tid >> 6;
    const int lane = tid & 63;
    const int ql = lane & 31, hi = lane >> 5;

    const size_t rowbase = ((size_t)b * T_SEQ) * C_EMB + (size_t)h * 64;
    const size_t vtbase  = ((size_t)b * 1024 + (size_t)h * 64) * T_SEQ;

    const int srow = lane >> 3;
    const int scol = ((lane & 7) ^ srow) * 8;

    const int q0  = grp * 128;
    const int qw0 = q0 + w * 32;
    const int ntiles = 2 * grp + 2;

    short8 qf[4];
    #pragma unroll
    for (int ds = 0; ds < 4; ++ds)
        qf[ds] = *(const short8*)&Q[rowbase + (size_t)(qw0 + ql) * C_EMB + ds * 16 + hi * 8];

    f32x16 o0 = {}, o1 = {};
    float mrun = -1e30f, lsum = 0.0f;

    #pragma unroll
    for (int i = 0; i < 2; ++i) {
        int cb = w * 2 + i;
        async_load16(&Kg[rowbase + (size_t)(cb * 8 + srow) * C_EMB + scol],
                     (char*)Ks[0] + cb * 1024);
    }

    #pragma unroll 1
    for (int t = 0; t < ntiles; ++t) {
        const int kv0 = t * 64;
        const int cur = t & 1, nxt = cur ^ 1;
        __syncthreads();

        const bool active = (kv0 <= qw0 + 31);

        short8 vf0[4], vf1[4];
        if (active) {
            #pragma unroll
            for (int ks = 0; ks < 4; ++ks) {
                vf0[ks] = *(const short8*)&Vt[vtbase + (size_t)ql * T_SEQ + kv0 + ks * 16 + hi * 8];
                vf1[ks] = *(const short8*)&Vt[vtbase + (size_t)(32 + ql) * T_SEQ + kv0 + ks * 16 + hi * 8];
            }
        }
        if (t + 1 < ntiles) {
            #pragma unroll
            for (int i = 0; i < 2; ++i) {
                int cb = w * 2 + i;
                async_load16(&Kg[rowbase + (size_t)(kv0 + 64 + cb * 8 + srow) * C_EMB + scol],
                             (char*)Ks[nxt] + cb * 1024);
            }
        }
        if (!active) continue;

        f32x16 sa0 = {}, sa1 = {};
        __builtin_amdgcn_s_setprio(1);
        #pragma unroll
        for (int ds = 0; ds < 4; ++ds) {
            short8 a0 = *(const short8*)((const char*)Ks[cur] + (ql) * 128 +
                                         ((ds * 32 + hi * 16) ^ ((ql & 7) << 4)));
            short8 a1 = *(const short8*)((const char*)Ks[cur] + (32 + ql) * 128 +
                                         ((ds * 32 + hi * 16) ^ ((ql & 7) << 4)));
            sa0 = __builtin_amdgcn_mfma_f32_32x32x16_bf16(a0, qf[ds], sa0, 0, 0, 0);
            sa1 = __builtin_amdgcn_mfma_f32_32x32x16_bf16(a1, qf[ds], sa1, 0, 0, 0);
        }
        __builtin_amdgcn_s_setprio(0);

        if (kv0 + 63 > qw0) {
            const int qi = qw0 + ql;
            #pragma unroll
            for (int r = 0; r < 16; ++r) {
                int kl = (r & 3) + 8 * (r >> 2) + 4 * hi;
                if (kv0 + kl > qi)      sa0[r] = -1e30f;
                if (kv0 + 32 + kl > qi) sa1[r] = -1e30f;
            }
        }

        float mx[8];
        #pragma unroll
        for (int r = 0; r < 8; ++r)
            mx[r] = fmaxf(fmaxf(sa0[r], sa0[r + 8]), fmaxf(sa1[r], sa1[r + 8]));
        mx[0] = fmaxf(mx[0], mx[4]); mx[1] = fmaxf(mx[1], mx[5]);
        mx[2] = fmaxf(mx[2], mx[6]); mx[3] = fmaxf(mx[3], mx[7]);
        float tmax = fmaxf(fmaxf(mx[0], mx[1]), fmaxf(mx[2], mx[3]));
        tmax = plswap_max(tmax);
        if (!__all(tmax <= mrun + 8.0f)) {
            float mn  = fmaxf(mrun, tmax);
            float scl = exp2f(mrun - mn);
            mrun = mn;
            lsum *= scl;
            #pragma unroll
            for (int gg = 0; gg < 4; ++gg)
                #pragma unroll
                for (int r2 = 0; r2 < 4; ++r2) {
                    float sc = __shfl(scl, gg * 8 + 4 * hi + r2);
                    o0[gg * 4 + r2] *= sc;
                    o1[gg * 4 + r2] *= sc;
                }
        }
        #pragma unroll
        for (int r = 0; r < 16; ++r) {
            sa0[r] = exp2f(sa0[r] - mrun);
            sa1[r] = exp2f(sa1[r] - mrun);
        }
        float sm[8];
        #pragma unroll
        for (int r = 0; r < 8; ++r)
            sm[r] = (sa0[r] + sa0[r + 8]) + (sa1[r] + sa1[r + 8]);
        lsum += ((sm[0] + sm[1]) + (sm[2] + sm[3])) + ((sm[4] + sm[5]) + (sm[6] + sm[7]));

        unsigned pw0[8], pw1[8];
        #pragma unroll
        for (int gg = 0; gg < 4; ++gg)
            #pragma unroll
            for (int hh = 0; hh < 2; ++hh) {
                asm("v_cvt_pk_bf16_f32 %0, %1, %2"
                    : "=v"(pw0[gg * 2 + hh]) : "v"(sa0[4 * gg + 2 * hh]), "v"(sa0[4 * gg + 2 * hh + 1]));
                asm("v_cvt_pk_bf16_f32 %0, %1, %2"
                    : "=v"(pw1[gg * 2 + hh]) : "v"(sa1[4 * gg + 2 * hh]), "v"(sa1[4 * gg + 2 * hh + 1]));
            }

        short8 pf[4];
        #pragma unroll
        for (int ks = 0; ks < 4; ++ks) {
            const int g0 = (2 * ks) & 3, g1 = (2 * ks + 1) & 3;
            unsigned p0, q0c, p1, q1c;
            if (ks < 2) { p0 = pw0[g0 * 2]; p1 = pw0[g0 * 2 + 1];
                          q0c = pw0[g1 * 2]; q1c = pw0[g1 * 2 + 1]; }
            else        { p0 = pw1[g0 * 2]; p1 = pw1[g0 * 2 + 1];
                          q0c = pw1[g1 * 2]; q1c = pw1[g1 * 2 + 1]; }
            plswap_u(p0, q0c);
            plswap_u(p1, q1c);
            union { unsigned u[4]; short8 v; } uu;
            uu.u[0] = p0;
            uu.u[1] = p1;
            uu.u[2] = q0c;
            uu.u[3] = q1c;
            pf[ks] = uu.v;
        }

        __builtin_amdgcn_s_setprio(1);
        #pragma unroll
        for (int ks = 0; ks < 4; ++ks) {
            o0 = __builtin_amdgcn_mfma_f32_32x32x16_bf16(pf[ks], vf0[ks], o0, 0, 0, 0);
            o1 = __builtin_amdgcn_mfma_f32_32x32x16_bf16(pf[ks], vf1[ks], o1, 0, 0, 0);
        }
        __builtin_amdgcn_s_setprio(0);
    }

    lsum = plswap_sum(lsum);
    float linv = 1.0f / lsum;
    #pragma unroll
    for (int gg = 0; gg < 4; ++gg)
        #pragma unroll
        for (int r2 = 0; r2 < 4; ++r2) {
            int row = gg * 8 + 4 * hi + r2;
            float li = __shfl(linv, row);
            size_t ybase = rowbase + (size_t)(qw0 + row) * C_EMB;
            Y[ybase + ql]      = f2bf(o0[gg * 4 + r2] * li);
            Y[ybase + 32 + ql] = f2bf(o1[gg * 4 + r2] * li);
        }
}

// ---------------- launcher ----------------
extern "C" void kernel_launch(void* const* d_in, const int* in_sizes, int n_in,
                              void* d_out, int out_size, void* d_ws, size_t ws_size,
                              hipStream_t stream) {
    const float* x  = (const float*)d_in[0];
    const float* Wk = (const float*)d_in[1];
    const float* bk = (const float*)d_in[2];
    const float* Wq = (const float*)d_in[3];
    const float* bq = (const float*)d_in[4];
    const float* Wv = (const float*)d_in[5];
    const float* bv = (const float*)d_in[6];
    const float* Wp = (const float*)d_in[7];
    const float* bp = (const float*)d_in[8];

    const size_t SX = (size_t)8192 * 1024;
    const size_t SW = (size_t)1024 * 1024;

    char* ws = (char*)d_ws;
    unsigned short* xb   = (unsigned short*)ws; ws += SX * 2;
    unsigned short* Wqkv = (unsigned short*)ws; ws += 3 * SW * 2;  // [Wq;Wk;Wv] rows
    unsigned short* Wpb  = (unsigned short*)ws; ws += SW * 2;
    unsigned short* qb   = (unsigned short*)ws; ws += SX * 2;
    unsigned short* kb   = (unsigned short*)ws; ws += SX * 2;
    unsigned short* vtb  = (unsigned short*)ws; ws += SX * 2;  // V^T per head [b][h][d][t]
    unsigned short* yb   = (unsigned short*)ws; ws += SX * 2;

    cvt_all<<<dim3(12288), 256, 0, stream>>>(x, Wq, Wk, Wv, Wp, xb, Wqkv, Wpb);

    gemm_qkv8<<<dim3(12, 32), 512, 0, stream>>>(xb, Wqkv, bq, bk, bv, qb, kb, vtb);

    attn_fwd16<<<dim3(1024), 256, 0, stream>>>(qb, kb, vtb, yb);

    gemm_proj<<<dim3(8, 64), 256, 0, stream>>>(yb, Wpb, bp, (float*)d_out, 8192, 1024, 1024);
}

// Round 17
// 203.357 us; speedup vs baseline: 1.0549x; 1.0055x over previous
//
#include <hip/hip_runtime.h>

typedef __attribute__((ext_vector_type(8))) short short8;
typedef __attribute__((ext_vector_type(4))) float f32x4;
typedef __attribute__((ext_vector_type(16))) float f32x16;
typedef __attribute__((ext_vector_type(4))) unsigned short u16x4;
typedef __attribute__((ext_vector_type(4))) float float4v;

#define AS1 __attribute__((address_space(1)))
#define AS3 __attribute__((address_space(3)))

#define T_SEQ 2048
#define C_EMB 1024
#define NHEAD 16
#define NB    4
#define SCL_Q 0.18033688f   // 0.125 * log2(e)

__device__ __forceinline__ unsigned short f2bf(float f) {
    union { float f; unsigned u; } cv; cv.f = f;
    unsigned u = cv.u;
    unsigned r = (u + 0x7FFFu + ((u >> 16) & 1u)) >> 16;
    return (unsigned short)r;
}

__device__ __forceinline__ void async_load16(const void* g, void* l) {
    __builtin_amdgcn_global_load_lds((const AS1 unsigned*)g, (AS3 unsigned*)l, 16, 0, 0);
}

// permlane32_swap builtin (R12-proven)
__device__ __forceinline__ void plswap_u(unsigned &a, unsigned &b) {
    auto r = __builtin_amdgcn_permlane32_swap(a, b, false, false);
    a = r[0]; b = r[1];
}
__device__ __forceinline__ float plswap_max(float t) {
    union { float f; unsigned u; } c; c.f = t;
    auto r = __builtin_amdgcn_permlane32_swap(c.u, c.u, false, false);
    union { unsigned u; float f; } x0, x1; x0.u = r[0]; x1.u = r[1];
    return fmaxf(x0.f, x1.f);
}
__device__ __forceinline__ float plswap_sum(float t) {
    union { float f; unsigned u; } c; c.f = t;
    auto r = __builtin_amdgcn_permlane32_swap(c.u, c.u, false, false);
    union { unsigned u; float f; } x0, x1; x0.u = r[0]; x1.u = r[1];
    return x0.f + x1.f;
}

// ---------------- fused f32 -> bf16 convert ----------------
__global__ void cvt_all(const float* __restrict__ x,
                        const float* __restrict__ wq, const float* __restrict__ wk,
                        const float* __restrict__ wv, const float* __restrict__ wp,
                        unsigned short* __restrict__ xb,
                        unsigned short* __restrict__ wqkv,
                        unsigned short* __restrict__ wpb) {
    const int blk = blockIdx.x;
    const float* src; unsigned short* dst; int idx;
    if (blk < 8192) {
        src = x; dst = xb; idx = blk * 256 + threadIdx.x;
    } else {
        int wsel = (blk - 8192) >> 10;
        idx = ((blk - 8192) & 1023) * 256 + threadIdx.x;
        src = (wsel == 0) ? wq : (wsel == 1) ? wk : (wsel == 2) ? wv : wp;
        dst = (wsel == 3) ? wpb : wqkv + (size_t)wsel * 1048576;
    }
    float4v v = ((const float4v*)src)[idx];
    u16x4 o;
    o[0] = f2bf(v[0]); o[1] = f2bf(v[1]); o[2] = f2bf(v[2]); o[3] = f2bf(v[3]);
    ((u16x4*)dst)[idx] = o;
}

// ---------------- QKV GEMM, 256x256 8-phase schedule, COUNTED-WAIT fix ----------------
// R16's structure with the T4 violation removed:
//  * all 8 next-tile stage loads issued in phases 0-1 (4+4) -> youngest load is
//    >=2 phases (~600-1000cy) old at the drain point;
//  * the only vmcnt in the main loop is folded just before phase 3's closing
//    barrier (aged loads -> near-free), no per-phase drain;
//  * phase = {ds_read quadrant || stage-issue -> s_barrier -> lgkmcnt(0)+
//    sched_barrier -> setprio(1) 16 MFMA setprio(0) -> s_barrier}.
__global__ __launch_bounds__(512, 2) void gemm_qkv8(const unsigned short* __restrict__ A,
                                                    const unsigned short* __restrict__ W,
                                                    const float* __restrict__ bq,
                                                    const float* __restrict__ bk,
                                                    const float* __restrict__ bv,
                                                    unsigned short* __restrict__ Qo,
                                                    unsigned short* __restrict__ Ko,
                                                    unsigned short* __restrict__ Vt) {
    __shared__ __align__(16) unsigned short Abuf[2][256 * 64];   // 2 x 32KB
    __shared__ __align__(16) unsigned short Bbuf[2][256 * 64];   // 2 x 32KB

    const int tid  = threadIdx.x;
    const int wid  = tid >> 6;
    const int lane = tid & 63;
    const int lr = lane & 15, lg = lane >> 4;
    const int wr = wid >> 2, wc = wid & 3;        // 2M x 4N wave grid
    const int n0 = blockIdx.x * 256;
    const int m0 = blockIdx.y * 256;
    const int K  = 1024;

    const int srow = tid >> 3;                    // 0..63 within 64-row chunk
    const int sgE  = ((tid & 7) ^ (srow & 7)) * 8; // pre-swizzled global granule

    f32x4 acc[8][4] = {};

    // prologue: stage K-tile 0 into buf 0
    #pragma unroll
    for (int j = 0; j < 4; ++j) {
        async_load16(&A[(size_t)(m0 + j * 64 + srow) * K + sgE],
                     (char*)Abuf[0] + j * 8192 + tid * 16);
        async_load16(&W[(size_t)(n0 + j * 64 + srow) * K + sgE],
                     (char*)Bbuf[0] + j * 8192 + tid * 16);
    }
    asm volatile("s_waitcnt vmcnt(0)" ::: "memory");
    __builtin_amdgcn_s_barrier();

    #pragma unroll 1
    for (int t = 0; t < 16; ++t) {
        const int cur = t & 1, nxt = cur ^ 1;
        const unsigned short* Ac = Abuf[cur];
        const unsigned short* Bc = Bbuf[cur];

        #pragma unroll
        for (int q = 0; q < 4; ++q) {             // quadrant phase: mh=q>>1, nh=q&1
            const int mh = q >> 1, nh = q & 1;

            // ---- ds_read this quadrant's fragments ----
            short8 af[4][2], bf[2][2];
            #pragma unroll
            for (int mi = 0; mi < 4; ++mi) {
                int row = wr * 128 + (mh * 4 + mi) * 16 + lr;
                #pragma unroll
                for (int ks = 0; ks < 2; ++ks)
                    af[mi][ks] = *(const short8*)((const char*)Ac + row * 128 +
                                                  ((ks * 64 + lg * 16) ^ ((lr & 7) << 4)));
            }
            #pragma unroll
            for (int ni = 0; ni < 2; ++ni) {
                int brow = wc * 64 + (nh * 2 + ni) * 16 + lr;
                #pragma unroll
                for (int ks = 0; ks < 2; ++ks)
                    bf[ni][ks] = *(const short8*)((const char*)Bc + brow * 128 +
                                                  ((ks * 64 + lg * 16) ^ ((lr & 7) << 4)));
            }
            // ---- stage next tile EARLY: phases 0-1 issue all 8 loads ----
            if (t + 1 < 16 && q < 2) {
                #pragma unroll
                for (int jj = 0; jj < 2; ++jj) {
                    int j = q * 2 + jj;
                    async_load16(&A[(size_t)(m0 + j * 64 + srow) * K + (t + 1) * 64 + sgE],
                                 (char*)Abuf[nxt] + j * 8192 + tid * 16);
                    async_load16(&W[(size_t)(n0 + j * 64 + srow) * K + (t + 1) * 64 + sgE],
                                 (char*)Bbuf[nxt] + j * 8192 + tid * 16);
                }
            }
            __builtin_amdgcn_s_barrier();
            asm volatile("s_waitcnt lgkmcnt(0)" ::: "memory");
            __builtin_amdgcn_sched_barrier(0);    // rule 18
            __builtin_amdgcn_s_setprio(1);
            #pragma unroll
            for (int ks = 0; ks < 2; ++ks)
                #pragma unroll
                for (int mi = 0; mi < 4; ++mi)
                    #pragma unroll
                    for (int ni = 0; ni < 2; ++ni)
                        acc[mh * 4 + mi][nh * 2 + ni] =
                            __builtin_amdgcn_mfma_f32_16x16x32_bf16(
                                af[mi][ks], bf[ni][ks], acc[mh * 4 + mi][nh * 2 + ni], 0, 0, 0);
            __builtin_amdgcn_s_setprio(0);
            // drain next-tile loads ONLY at iter end (loads are >=2 phases old)
            if (q == 3)
                asm volatile("s_waitcnt vmcnt(0)" ::: "memory");
            __builtin_amdgcn_s_barrier();
        }
    }

    // ---- epilogue ----
    const int sel = n0 >> 10;                     // 0=Q 1=K 2=V
    const int nl0 = n0 & 1023;
    const float* bias = (sel == 0) ? bq : (sel == 1) ? bk : bv;
    const float scale = (sel == 0) ? SCL_Q : 1.0f;

    #pragma unroll
    for (int nf = 0; nf < 4; ++nf) {
        int cc = nl0 + wc * 64 + nf * 16 + lr;
        float bvv = bias[cc];
        #pragma unroll
        for (int mf = 0; mf < 8; ++mf) {
            int rr0 = m0 + wr * 128 + mf * 16 + lg * 4;
            u16x4 pk;
            #pragma unroll
            for (int r = 0; r < 4; ++r)
                pk[r] = f2bf((acc[mf][nf][r] + bvv) * scale);
            if (sel == 2) {
                size_t idx = ((size_t)(rr0 >> 11) * 1024 + cc) * 2048 + (rr0 & 2047);
                *(u16x4*)&Vt[idx] = pk;
            } else {
                unsigned short* out = (sel == 0) ? Qo : Ko;
                #pragma unroll
                for (int r = 0; r < 4; ++r)
                    out[(size_t)(rr0 + r) * 1024 + cc] = pk[r];
            }
        }
    }
}

// ---------------- proj GEMM: C[M,N] = A[M,K]*B[N,K]^T + bias (f32 out, 128-tile) ----------------
__global__ void gemm_proj(const unsigned short* __restrict__ A,
                          const unsigned short* __restrict__ B,
                          const float* __restrict__ bias,
                          float* __restrict__ Cout,
                          int M, int N, int K) {
    __shared__ __align__(16) unsigned short As[128 * 32];
    __shared__ __align__(16) unsigned short Bs[128 * 32];
    const int tid  = threadIdx.x;
    const int wid  = tid >> 6;
    const int lane = tid & 63;
    const int lg = lane >> 4, lr = lane & 15;
    const int wr = wid >> 1, wc = wid & 1;
    const int n0 = blockIdx.x * 128;
    const int m0 = blockIdx.y * 128;

    f32x4 acc[4][4] = {};

    for (int kt = 0; kt < K; kt += 32) {
        #pragma unroll
        for (int r = 0; r < 2; ++r) {
            int cb = r * 4 + wid;
            int chunk = cb * 64 + lane;
            int row = chunk >> 2;
            int col = (chunk & 3) * 8;
            async_load16(&A[(size_t)(m0 + row) * K + kt + col], (char*)As + cb * 1024);
            async_load16(&B[(size_t)(n0 + row) * K + kt + col], (char*)Bs + cb * 1024);
        }
        __syncthreads();
        short8 af[4], bfr[4];
        #pragma unroll
        for (int m = 0; m < 4; ++m)
            af[m] = *(const short8*)&As[(wr * 64 + m * 16 + lr) * 32 + lg * 8];
        #pragma unroll
        for (int n = 0; n < 4; ++n)
            bfr[n] = *(const short8*)&Bs[(wc * 64 + n * 16 + lr) * 32 + lg * 8];
        #pragma unroll
        for (int m = 0; m < 4; ++m)
            #pragma unroll
            for (int n = 0; n < 4; ++n)
                acc[m][n] = __builtin_amdgcn_mfma_f32_16x16x32_bf16(af[m], bfr[n], acc[m][n], 0, 0, 0);
        __syncthreads();
    }

    #pragma unroll
    for (int n = 0; n < 4; ++n) {
        int cc = n0 + wc * 64 + n * 16 + lr;
        float bvv = bias[cc];
        #pragma unroll
        for (int m = 0; m < 4; ++m) {
            int rr0 = m0 + wr * 64 + m * 16 + lg * 4;
            #pragma unroll
            for (int r = 0; r < 4; ++r)
                Cout[(size_t)(rr0 + r) * N + cc] = acc[m][n][r] + bvv;
        }
    }
}

// ---------------- flash attention (R14-proven: 4-wave 32x32, 90us) ----------------
__global__ __launch_bounds__(256, 2) void attn_fwd17(const unsigned short* __restrict__ Q,
                                                     const unsigned short* __restrict__ Kg,
                                                     const unsigned short* __restrict__ Vt,
                                                     unsigned short* __restrict__ Y) {
    __shared__ __align__(16) unsigned short Ks[2][64 * 64];

    const int bid = blockIdx.x;
    const int xcd = bid & 7;
    const int s   = bid >> 3;
    const int grp = 15 - (s >> 3);
    const int bh  = (s & 7) * 8 + xcd;
    const int h   = bh & 15;
    const int b   = bh >> 4;

    const int tid  = threadIdx.x;
    const int w    = tid >> 6;
    const int lane = tid & 63;
    const int ql = lane & 31, hi = lane >> 5;

    const size_t rowbase = ((size_t)b * T_SEQ) * C_EMB + (size_t)h * 64;
    const size_t vtbase  = ((size_t)b * 1024 + (size_t)h * 64) * T_SEQ;

    const int srow = lane >> 3;
    const int scol = ((lane & 7) ^ srow) * 8;

    const int q0  = grp * 128;
    const int qw0 = q0 + w * 32;
    const int ntiles = 2 * grp + 2;

    short8 qf[4];
    #pragma unroll
    for (int ds = 0; ds < 4; ++ds)
        qf[ds] = *(const short8*)&Q[rowbase + (size_t)(qw0 + ql) * C_EMB + ds * 16 + hi * 8];

    f32x16 o0 = {}, o1 = {};
    float mrun = -1e30f, lsum = 0.0f;

    #pragma unroll
    for (int i = 0; i < 2; ++i) {
        int cb = w * 2 + i;
        async_load16(&Kg[rowbase + (size_t)(cb * 8 + srow) * C_EMB + scol],
                     (char*)Ks[0] + cb * 1024);
    }

    #pragma unroll 1
    for (int t = 0; t < ntiles; ++t) {
        const int kv0 = t * 64;
        const int cur = t & 1, nxt = cur ^ 1;
        __syncthreads();

        const bool active = (kv0 <= qw0 + 31);

        short8 vf0[4], vf1[4];
        if (active) {
            #pragma unroll
            for (int ks = 0; ks < 4; ++ks) {
                vf0[ks] = *(const short8*)&Vt[vtbase + (size_t)ql * T_SEQ + kv0 + ks * 16 + hi * 8];
                vf1[ks] = *(const short8*)&Vt[vtbase + (size_t)(32 + ql) * T_SEQ + kv0 + ks * 16 + hi * 8];
            }
        }
        if (t + 1 < ntiles) {
            #pragma unroll
            for (int i = 0; i < 2; ++i) {
                int cb = w * 2 + i;
                async_load16(&Kg[rowbase + (size_t)(kv0 + 64 + cb * 8 + srow) * C_EMB + scol],
                             (char*)Ks[nxt] + cb * 1024);
            }
        }
        if (!active) continue;

        f32x16 sa0 = {}, sa1 = {};
        __builtin_amdgcn_s_setprio(1);
        #pragma unroll
        for (int ds = 0; ds < 4; ++ds) {
            short8 a0 = *(const short8*)((const char*)Ks[cur] + (ql) * 128 +
                                         ((ds * 32 + hi * 16) ^ ((ql & 7) << 4)));
            short8 a1 = *(const short8*)((const char*)Ks[cur] + (32 + ql) * 128 +
                                         ((ds * 32 + hi * 16) ^ ((ql & 7) << 4)));
            sa0 = __builtin_amdgcn_mfma_f32_32x32x16_bf16(a0, qf[ds], sa0, 0, 0, 0);
            sa1 = __builtin_amdgcn_mfma_f32_32x32x16_bf16(a1, qf[ds], sa1, 0, 0, 0);
        }
        __builtin_amdgcn_s_setprio(0);

        if (kv0 + 63 > qw0) {
            const int qi = qw0 + ql;
            #pragma unroll
            for (int r = 0; r < 16; ++r) {
                int kl = (r & 3) + 8 * (r >> 2) + 4 * hi;
                if (kv0 + kl > qi)      sa0[r] = -1e30f;
                if (kv0 + 32 + kl > qi) sa1[r] = -1e30f;
            }
        }

        float mx[8];
        #pragma unroll
        for (int r = 0; r < 8; ++r)
            mx[r] = fmaxf(fmaxf(sa0[r], sa0[r + 8]), fmaxf(sa1[r], sa1[r + 8]));
        mx[0] = fmaxf(mx[0], mx[4]); mx[1] = fmaxf(mx[1], mx[5]);
        mx[2] = fmaxf(mx[2], mx[6]); mx[3] = fmaxf(mx[3], mx[7]);
        float tmax = fmaxf(fmaxf(mx[0], mx[1]), fmaxf(mx[2], mx[3]));
        tmax = plswap_max(tmax);
        if (!__all(tmax <= mrun + 8.0f)) {
            float mn  = fmaxf(mrun, tmax);
            float scl = exp2f(mrun - mn);
            mrun = mn;
            lsum *= scl;
            #pragma unroll
            for (int gg = 0; gg < 4; ++gg)
                #pragma unroll
                for (int r2 = 0; r2 < 4; ++r2) {
                    float sc = __shfl(scl, gg * 8 + 4 * hi + r2);
                    o0[gg * 4 + r2] *= sc;
                    o1[gg * 4 + r2] *= sc;
                }
        }
        #pragma unroll
        for (int r = 0; r < 16; ++r) {
            sa0[r] = exp2f(sa0[r] - mrun);
            sa1[r] = exp2f(sa1[r] - mrun);
        }
        float sm[8];
        #pragma unroll
        for (int r = 0; r < 8; ++r)
            sm[r] = (sa0[r] + sa0[r + 8]) + (sa1[r] + sa1[r + 8]);
        lsum += ((sm[0] + sm[1]) + (sm[2] + sm[3])) + ((sm[4] + sm[5]) + (sm[6] + sm[7]));

        unsigned pw0[8], pw1[8];
        #pragma unroll
        for (int gg = 0; gg < 4; ++gg)
            #pragma unroll
            for (int hh = 0; hh < 2; ++hh) {
                asm("v_cvt_pk_bf16_f32 %0, %1, %2"
                    : "=v"(pw0[gg * 2 + hh]) : "v"(sa0[4 * gg + 2 * hh]), "v"(sa0[4 * gg + 2 * hh + 1]));
                asm("v_cvt_pk_bf16_f32 %0, %1, %2"
                    : "=v"(pw1[gg * 2 + hh]) : "v"(sa1[4 * gg + 2 * hh]), "v"(sa1[4 * gg + 2 * hh + 1]));
            }

        short8 pf[4];
        #pragma unroll
        for (int ks = 0; ks < 4; ++ks) {
            const int g0 = (2 * ks) & 3, g1 = (2 * ks + 1) & 3;
            unsigned p0, q0c, p1, q1c;
            if (ks < 2) { p0 = pw0[g0 * 2]; p1 = pw0[g0 * 2 + 1];
                          q0c = pw0[g1 * 2]; q1c = pw0[g1 * 2 + 1]; }
            else        { p0 = pw1[g0 * 2]; p1 = pw1[g0 * 2 + 1];
                          q0c = pw1[g1 * 2]; q1c = pw1[g1 * 2 + 1]; }
            plswap_u(p0, q0c);
            plswap_u(p1, q1c);
            union { unsigned u[4]; short8 v; } uu;
            uu.u[0] = p0;
            uu.u[1] = p1;
            uu.u[2] = q0c;
            uu.u[3] = q1c;
            pf[ks] = uu.v;
        }

        __builtin_amdgcn_s_setprio(1);
        #pragma unroll
        for (int ks = 0; ks < 4; ++ks) {
            o0 = __builtin_amdgcn_mfma_f32_32x32x16_bf16(pf[ks], vf0[ks], o0, 0, 0, 0);
            o1 = __builtin_amdgcn_mfma_f32_32x32x16_bf16(pf[ks], vf1[ks], o1, 0, 0, 0);
        }
        __builtin_amdgcn_s_setprio(0);
    }

    lsum = plswap_sum(lsum);
    float linv = 1.0f / lsum;
    #pragma unroll
    for (int gg = 0; gg < 4; ++gg)
        #pragma unroll
        for (int r2 = 0; r2 < 4; ++r2) {
            int row = gg * 8 + 4 * hi + r2;
            float li = __shfl(linv, row);
            size_t ybase = rowbase + (size_t)(qw0 + row) * C_EMB;
            Y[ybase + ql]      = f2bf(o0[gg * 4 + r2] * li);
            Y[ybase + 32 + ql] = f2bf(o1[gg * 4 + r2] * li);
        }
}

// ---------------- launcher ----------------
extern "C" void kernel_launch(void* const* d_in, const int* in_sizes, int n_in,
                              void* d_out, int out_size, void* d_ws, size_t ws_size,
                              hipStream_t stream) {
    const float* x  = (const float*)d_in[0];
    const float* Wk = (const float*)d_in[1];
    const float* bk = (const float*)d_in[2];
    const float* Wq = (const float*)d_in[3];
    const float* bq = (const float*)d_in[4];
    const float* Wv = (const float*)d_in[5];
    const float* bv = (const float*)d_in[6];
    const float* Wp = (const float*)d_in[7];
    const float* bp = (const float*)d_in[8];

    const size_t SX = (size_t)8192 * 1024;
    const size_t SW = (size_t)1024 * 1024;

    char* ws = (char*)d_ws;
    unsigned short* xb   = (unsigned short*)ws; ws += SX * 2;
    unsigned short* Wqkv = (unsigned short*)ws; ws += 3 * SW * 2;
    unsigned short* Wpb  = (unsigned short*)ws; ws += SW * 2;
    unsigned short* qb   = (unsigned short*)ws; ws += SX * 2;
    unsigned short* kb   = (unsigned short*)ws; ws += SX * 2;
    unsigned short* vtb  = (unsigned short*)ws; ws += SX * 2;
    unsigned short* yb   = (unsigned short*)ws; ws += SX * 2;

    cvt_all<<<dim3(12288), 256, 0, stream>>>(x, Wq, Wk, Wv, Wp, xb, Wqkv, Wpb);

    gemm_qkv8<<<dim3(12, 32), 512, 0, stream>>>(xb, Wqkv, bq, bk, bv, qb, kb, vtb);

    attn_fwd17<<<dim3(1024), 256, 0, stream>>>(qb, kb, vtb, yb);

    gemm_proj<<<dim3(8, 64), 256, 0, stream>>>(yb, Wpb, bp, (float*)d_out, 8192, 1024, 1024);
}

// Round 18
// 196.925 us; speedup vs baseline: 1.0893x; 1.0327x over previous
//
#include <hip/hip_runtime.h>

typedef __attribute__((ext_vector_type(8))) short short8;
typedef __attribute__((ext_vector_type(4))) float f32x4;
typedef __attribute__((ext_vector_type(16))) float f32x16;
typedef __attribute__((ext_vector_type(4))) unsigned short u16x4;
typedef __attribute__((ext_vector_type(4))) float float4v;

#define AS1 __attribute__((address_space(1)))
#define AS3 __attribute__((address_space(3)))

#define T_SEQ 2048
#define C_EMB 1024
#define NHEAD 16
#define NB    4
#define SCL_Q 0.18033688f   // 0.125 * log2(e)

__device__ __forceinline__ unsigned short f2bf(float f) {
    union { float f; unsigned u; } cv; cv.f = f;
    unsigned u = cv.u;
    unsigned r = (u + 0x7FFFu + ((u >> 16) & 1u)) >> 16;
    return (unsigned short)r;
}

__device__ __forceinline__ void async_load16(const void* g, void* l) {
    __builtin_amdgcn_global_load_lds((const AS1 unsigned*)g, (AS3 unsigned*)l, 16, 0, 0);
}

// permlane32_swap builtin (R12-proven)
__device__ __forceinline__ void plswap_u(unsigned &a, unsigned &b) {
    auto r = __builtin_amdgcn_permlane32_swap(a, b, false, false);
    a = r[0]; b = r[1];
}
__device__ __forceinline__ float plswap_max(float t) {
    union { float f; unsigned u; } c; c.f = t;
    auto r = __builtin_amdgcn_permlane32_swap(c.u, c.u, false, false);
    union { unsigned u; float f; } x0, x1; x0.u = r[0]; x1.u = r[1];
    return fmaxf(x0.f, x1.f);
}
__device__ __forceinline__ float plswap_sum(float t) {
    union { float f; unsigned u; } c; c.f = t;
    auto r = __builtin_amdgcn_permlane32_swap(c.u, c.u, false, false);
    union { unsigned u; float f; } x0, x1; x0.u = r[0]; x1.u = r[1];
    return x0.f + x1.f;
}

// ---------------- fused f32 -> bf16 convert ----------------
__global__ void cvt_all(const float* __restrict__ x,
                        const float* __restrict__ wq, const float* __restrict__ wk,
                        const float* __restrict__ wv, const float* __restrict__ wp,
                        unsigned short* __restrict__ xb,
                        unsigned short* __restrict__ wqkv,
                        unsigned short* __restrict__ wpb) {
    const int blk = blockIdx.x;
    const float* src; unsigned short* dst; int idx;
    if (blk < 8192) {
        src = x; dst = xb; idx = blk * 256 + threadIdx.x;
    } else {
        int wsel = (blk - 8192) >> 10;
        idx = ((blk - 8192) & 1023) * 256 + threadIdx.x;
        src = (wsel == 0) ? wq : (wsel == 1) ? wk : (wsel == 2) ? wv : wp;
        dst = (wsel == 3) ? wpb : wqkv + (size_t)wsel * 1048576;
    }
    float4v v = ((const float4v*)src)[idx];
    u16x4 o;
    o[0] = f2bf(v[0]); o[1] = f2bf(v[1]); o[2] = f2bf(v[2]); o[3] = f2bf(v[3]);
    ((u16x4*)dst)[idx] = o;
}

// ---------------- QKV GEMM, 256x256, gray-code 4-phase (exactly-once ds_read) ----------------
// Phase order (mh,nh): (0,0)->(0,1)->(1,1)->(1,0). P0 reads af0+bfA (12 b128),
// P1 reads bfB (4), P2 reads af1 (8, af0 dead), P3 reads NOTHING (af1,bfA live)
// -> 24 ds_read/wave/K-tile (was 48: the R16/R17 LDS-pipe bottleneck).
// Stage-early (4+4 loads in P0/P1), one vmcnt(0) at tile end (loads >=2 phases old).
__global__ __launch_bounds__(512, 2) void gemm_qkv8(const unsigned short* __restrict__ A,
                                                    const unsigned short* __restrict__ W,
                                                    const float* __restrict__ bq,
                                                    const float* __restrict__ bk,
                                                    const float* __restrict__ bv,
                                                    unsigned short* __restrict__ Qo,
                                                    unsigned short* __restrict__ Ko,
                                                    unsigned short* __restrict__ Vt) {
    __shared__ __align__(16) unsigned short Abuf[2][256 * 64];   // 2 x 32KB
    __shared__ __align__(16) unsigned short Bbuf[2][256 * 64];   // 2 x 32KB

    const int tid  = threadIdx.x;
    const int wid  = tid >> 6;
    const int lane = tid & 63;
    const int lr = lane & 15, lg = lane >> 4;
    const int wr = wid >> 2, wc = wid & 3;        // 2M x 4N wave grid
    const int n0 = blockIdx.x * 256;
    const int m0 = blockIdx.y * 256;
    const int K  = 1024;

    const int srow = tid >> 3;
    const int sgE  = ((tid & 7) ^ (srow & 7)) * 8;

    f32x4 acc[8][4] = {};

    // prologue: stage K-tile 0 into buf 0
    #pragma unroll
    for (int j = 0; j < 4; ++j) {
        async_load16(&A[(size_t)(m0 + j * 64 + srow) * K + sgE],
                     (char*)Abuf[0] + j * 8192 + tid * 16);
        async_load16(&W[(size_t)(n0 + j * 64 + srow) * K + sgE],
                     (char*)Bbuf[0] + j * 8192 + tid * 16);
    }
    asm volatile("s_waitcnt vmcnt(0)" ::: "memory");
    __builtin_amdgcn_s_barrier();

    #pragma unroll 1
    for (int t = 0; t < 16; ++t) {
        const int cur = t & 1, nxt = cur ^ 1;
        const char* Ac = (const char*)Abuf[cur];
        const char* Bc = (const char*)Bbuf[cur];
        const int sw = (lr & 7) << 4;

        short8 af[4][2], bfA[2][2], bfB[2][2];

        // ======== PHASE 0: (mh=0, nh=0) — read af(mh0) + bfA(nh0) ========
        #pragma unroll
        for (int mi = 0; mi < 4; ++mi) {
            int row = wr * 128 + mi * 16 + lr;
            #pragma unroll
            for (int ks = 0; ks < 2; ++ks)
                af[mi][ks] = *(const short8*)(Ac + row * 128 + ((ks * 64 + lg * 16) ^ sw));
        }
        #pragma unroll
        for (int ni = 0; ni < 2; ++ni) {
            int brow = wc * 64 + ni * 16 + lr;
            #pragma unroll
            for (int ks = 0; ks < 2; ++ks)
                bfA[ni][ks] = *(const short8*)(Bc + brow * 128 + ((ks * 64 + lg * 16) ^ sw));
        }
        if (t + 1 < 16) {
            #pragma unroll
            for (int j = 0; j < 2; ++j) {
                async_load16(&A[(size_t)(m0 + j * 64 + srow) * K + (t + 1) * 64 + sgE],
                             (char*)Abuf[nxt] + j * 8192 + tid * 16);
                async_load16(&W[(size_t)(n0 + j * 64 + srow) * K + (t + 1) * 64 + sgE],
                             (char*)Bbuf[nxt] + j * 8192 + tid * 16);
            }
        }
        __builtin_amdgcn_s_barrier();
        asm volatile("s_waitcnt lgkmcnt(0)" ::: "memory");
        __builtin_amdgcn_sched_barrier(0);
        __builtin_amdgcn_s_setprio(1);
        #pragma unroll
        for (int ks = 0; ks < 2; ++ks)
            #pragma unroll
            for (int mi = 0; mi < 4; ++mi)
                #pragma unroll
                for (int ni = 0; ni < 2; ++ni)
                    acc[mi][ni] = __builtin_amdgcn_mfma_f32_16x16x32_bf16(
                        af[mi][ks], bfA[ni][ks], acc[mi][ni], 0, 0, 0);
        __builtin_amdgcn_s_setprio(0);
        __builtin_amdgcn_s_barrier();

        // ======== PHASE 1: (mh=0, nh=1) — read bfB(nh1) only ========
        #pragma unroll
        for (int ni = 0; ni < 2; ++ni) {
            int brow = wc * 64 + (2 + ni) * 16 + lr;
            #pragma unroll
            for (int ks = 0; ks < 2; ++ks)
                bfB[ni][ks] = *(const short8*)(Bc + brow * 128 + ((ks * 64 + lg * 16) ^ sw));
        }
        if (t + 1 < 16) {
            #pragma unroll
            for (int j = 2; j < 4; ++j) {
                async_load16(&A[(size_t)(m0 + j * 64 + srow) * K + (t + 1) * 64 + sgE],
                             (char*)Abuf[nxt] + j * 8192 + tid * 16);
                async_load16(&W[(size_t)(n0 + j * 64 + srow) * K + (t + 1) * 64 + sgE],
                             (char*)Bbuf[nxt] + j * 8192 + tid * 16);
            }
        }
        __builtin_amdgcn_s_barrier();
        asm volatile("s_waitcnt lgkmcnt(0)" ::: "memory");
        __builtin_amdgcn_sched_barrier(0);
        __builtin_amdgcn_s_setprio(1);
        #pragma unroll
        for (int ks = 0; ks < 2; ++ks)
            #pragma unroll
            for (int mi = 0; mi < 4; ++mi)
                #pragma unroll
                for (int ni = 0; ni < 2; ++ni)
                    acc[mi][2 + ni] = __builtin_amdgcn_mfma_f32_16x16x32_bf16(
                        af[mi][ks], bfB[ni][ks], acc[mi][2 + ni], 0, 0, 0);
        __builtin_amdgcn_s_setprio(0);
        __builtin_amdgcn_s_barrier();

        // ======== PHASE 2: (mh=1, nh=1) — read af(mh1) only (af0 dead) ========
        #pragma unroll
        for (int mi = 0; mi < 4; ++mi) {
            int row = wr * 128 + (4 + mi) * 16 + lr;
            #pragma unroll
            for (int ks = 0; ks < 2; ++ks)
                af[mi][ks] = *(const short8*)(Ac + row * 128 + ((ks * 64 + lg * 16) ^ sw));
        }
        __builtin_amdgcn_s_barrier();
        asm volatile("s_waitcnt lgkmcnt(0)" ::: "memory");
        __builtin_amdgcn_sched_barrier(0);
        __builtin_amdgcn_s_setprio(1);
        #pragma unroll
        for (int ks = 0; ks < 2; ++ks)
            #pragma unroll
            for (int mi = 0; mi < 4; ++mi)
                #pragma unroll
                for (int ni = 0; ni < 2; ++ni)
                    acc[4 + mi][2 + ni] = __builtin_amdgcn_mfma_f32_16x16x32_bf16(
                        af[mi][ks], bfB[ni][ks], acc[4 + mi][2 + ni], 0, 0, 0);
        __builtin_amdgcn_s_setprio(0);
        __builtin_amdgcn_s_barrier();

        // ======== PHASE 3: (mh=1, nh=0) — NO reads (af1, bfA live); pure MFMA ========
        __builtin_amdgcn_s_setprio(1);
        #pragma unroll
        for (int ks = 0; ks < 2; ++ks)
            #pragma unroll
            for (int mi = 0; mi < 4; ++mi)
                #pragma unroll
                for (int ni = 0; ni < 2; ++ni)
                    acc[4 + mi][ni] = __builtin_amdgcn_mfma_f32_16x16x32_bf16(
                        af[mi][ks], bfA[ni][ks], acc[4 + mi][ni], 0, 0, 0);
        __builtin_amdgcn_s_setprio(0);
        // tile end: staged loads (issued P0/P1, >=2 phases old) must have landed
        asm volatile("s_waitcnt vmcnt(0)" ::: "memory");
        __builtin_amdgcn_s_barrier();
    }

    // ---- epilogue ----
    const int sel = n0 >> 10;
    const int nl0 = n0 & 1023;
    const float* bias = (sel == 0) ? bq : (sel == 1) ? bk : bv;
    const float scale = (sel == 0) ? SCL_Q : 1.0f;

    #pragma unroll
    for (int nf = 0; nf < 4; ++nf) {
        int cc = nl0 + wc * 64 + nf * 16 + lr;
        float bvv = bias[cc];
        #pragma unroll
        for (int mf = 0; mf < 8; ++mf) {
            int rr0 = m0 + wr * 128 + mf * 16 + lg * 4;
            u16x4 pk;
            #pragma unroll
            for (int r = 0; r < 4; ++r)
                pk[r] = f2bf((acc[mf][nf][r] + bvv) * scale);
            if (sel == 2) {
                size_t idx = ((size_t)(rr0 >> 11) * 1024 + cc) * 2048 + (rr0 & 2047);
                *(u16x4*)&Vt[idx] = pk;
            } else {
                unsigned short* out = (sel == 0) ? Qo : Ko;
                #pragma unroll
                for (int r = 0; r < 4; ++r)
                    out[(size_t)(rr0 + r) * 1024 + cc] = pk[r];
            }
        }
    }
}

// ---------------- proj GEMM (m97 128-tile) ----------------
__global__ void gemm_proj(const unsigned short* __restrict__ A,
                          const unsigned short* __restrict__ B,
                          const float* __restrict__ bias,
                          float* __restrict__ Cout,
                          int M, int N, int K) {
    __shared__ __align__(16) unsigned short As[128 * 32];
    __shared__ __align__(16) unsigned short Bs[128 * 32];
    const int tid  = threadIdx.x;
    const int wid  = tid >> 6;
    const int lane = tid & 63;
    const int lg = lane >> 4, lr = lane & 15;
    const int wr = wid >> 1, wc = wid & 1;
    const int n0 = blockIdx.x * 128;
    const int m0 = blockIdx.y * 128;

    f32x4 acc[4][4] = {};

    for (int kt = 0; kt < K; kt += 32) {
        #pragma unroll
        for (int r = 0; r < 2; ++r) {
            int cb = r * 4 + wid;
            int chunk = cb * 64 + lane;
            int row = chunk >> 2;
            int col = (chunk & 3) * 8;
            async_load16(&A[(size_t)(m0 + row) * K + kt + col], (char*)As + cb * 1024);
            async_load16(&B[(size_t)(n0 + row) * K + kt + col], (char*)Bs + cb * 1024);
        }
        __syncthreads();
        short8 af[4], bfr[4];
        #pragma unroll
        for (int m = 0; m < 4; ++m)
            af[m] = *(const short8*)&As[(wr * 64 + m * 16 + lr) * 32 + lg * 8];
        #pragma unroll
        for (int n = 0; n < 4; ++n)
            bfr[n] = *(const short8*)&Bs[(wc * 64 + n * 16 + lr) * 32 + lg * 8];
        #pragma unroll
        for (int m = 0; m < 4; ++m)
            #pragma unroll
            for (int n = 0; n < 4; ++n)
                acc[m][n] = __builtin_amdgcn_mfma_f32_16x16x32_bf16(af[m], bfr[n], acc[m][n], 0, 0, 0);
        __syncthreads();
    }

    #pragma unroll
    for (int n = 0; n < 4; ++n) {
        int cc = n0 + wc * 64 + n * 16 + lr;
        float bvv = bias[cc];
        #pragma unroll
        for (int m = 0; m < 4; ++m) {
            int rr0 = m0 + wr * 64 + m * 16 + lg * 4;
            #pragma unroll
            for (int r = 0; r < 4; ++r)
                Cout[(size_t)(rr0 + r) * N + cc] = acc[m][n][r] + bvv;
        }
    }
}

// ---------------- flash attention (R14-proven: 4-wave 32x32, 90us) ----------------
__global__ __launch_bounds__(256, 2) void attn_fwd18(const unsigned short* __restrict__ Q,
                                                     const unsigned short* __restrict__ Kg,
                                                     const unsigned short* __restrict__ Vt,
                                                     unsigned short* __restrict__ Y) {
    __shared__ __align__(16) unsigned short Ks[2][64 * 64];

    const int bid = blockIdx.x;
    const int xcd = bid & 7;
    const int s   = bid >> 3;
    const int grp = 15 - (s >> 3);
    const int bh  = (s & 7) * 8 + xcd;
    const int h   = bh & 15;
    const int b   = bh >> 4;

    const int tid  = threadIdx.x;
    const int w    = tid >> 6;
    const int lane = tid & 63;
    const int ql = lane & 31, hi = lane >> 5;

    const size_t rowbase = ((size_t)b * T_SEQ) * C_EMB + (size_t)h * 64;
    const size_t vtbase  = ((size_t)b * 1024 + (size_t)h * 64) * T_SEQ;

    const int srow = lane >> 3;
    const int scol = ((lane & 7) ^ srow) * 8;

    const int q0  = grp * 128;
    const int qw0 = q0 + w * 32;
    const int ntiles = 2 * grp + 2;

    short8 qf[4];
    #pragma unroll
    for (int ds = 0; ds < 4; ++ds)
        qf[ds] = *(const short8*)&Q[rowbase + (size_t)(qw0 + ql) * C_EMB + ds * 16 + hi * 8];

    f32x16 o0 = {}, o1 = {};
    float mrun = -1e30f, lsum = 0.0f;

    #pragma unroll
    for (int i = 0; i < 2; ++i) {
        int cb = w * 2 + i;
        async_load16(&Kg[rowbase + (size_t)(cb * 8 + srow) * C_EMB + scol],
                     (char*)Ks[0] + cb * 1024);
    }

    #pragma unroll 1
    for (int t = 0; t < ntiles; ++t) {
        const int kv0 = t * 64;
        const int cur = t & 1, nxt = cur ^ 1;
        __syncthreads();

        const bool active = (kv0 <= qw0 + 31);

        short8 vf0[4], vf1[4];
        if (active) {
            #pragma unroll
            for (int ks = 0; ks < 4; ++ks) {
                vf0[ks] = *(const short8*)&Vt[vtbase + (size_t)ql * T_SEQ + kv0 + ks * 16 + hi * 8];
                vf1[ks] = *(const short8*)&Vt[vtbase + (size_t)(32 + ql) * T_SEQ + kv0 + ks * 16 + hi * 8];
            }
        }
        if (t + 1 < ntiles) {
            #pragma unroll
            for (int i = 0; i < 2; ++i) {
                int cb = w * 2 + i;
                async_load16(&Kg[rowbase + (size_t)(kv0 + 64 + cb * 8 + srow) * C_EMB + scol],
                             (char*)Ks[nxt] + cb * 1024);
            }
        }
        if (!active) continue;

        f32x16 sa0 = {}, sa1 = {};
        __builtin_amdgcn_s_setprio(1);
        #pragma unroll
        for (int ds = 0; ds < 4; ++ds) {
            short8 a0 = *(const short8*)((const char*)Ks[cur] + (ql) * 128 +
                                         ((ds * 32 + hi * 16) ^ ((ql & 7) << 4)));
            short8 a1 = *(const short8*)((const char*)Ks[cur] + (32 + ql) * 128 +
                                         ((ds * 32 + hi * 16) ^ ((ql & 7) << 4)));
            sa0 = __builtin_amdgcn_mfma_f32_32x32x16_bf16(a0, qf[ds], sa0, 0, 0, 0);
            sa1 = __builtin_amdgcn_mfma_f32_32x32x16_bf16(a1, qf[ds], sa1, 0, 0, 0);
        }
        __builtin_amdgcn_s_setprio(0);

        if (kv0 + 63 > qw0) {
            const int qi = qw0 + ql;
            #pragma unroll
            for (int r = 0; r < 16; ++r) {
                int kl = (r & 3) + 8 * (r >> 2) + 4 * hi;
                if (kv0 + kl > qi)      sa0[r] = -1e30f;
                if (kv0 + 32 + kl > qi) sa1[r] = -1e30f;
            }
        }

        float mx[8];
        #pragma unroll
        for (int r = 0; r < 8; ++r)
            mx[r] = fmaxf(fmaxf(sa0[r], sa0[r + 8]), fmaxf(sa1[r], sa1[r + 8]));
        mx[0] = fmaxf(mx[0], mx[4]); mx[1] = fmaxf(mx[1], mx[5]);
        mx[2] = fmaxf(mx[2], mx[6]); mx[3] = fmaxf(mx[3], mx[7]);
        float tmax = fmaxf(fmaxf(mx[0], mx[1]), fmaxf(mx[2], mx[3]));
        tmax = plswap_max(tmax);
        if (!__all(tmax <= mrun + 8.0f)) {
            float mn  = fmaxf(mrun, tmax);
            float scl = exp2f(mrun - mn);
            mrun = mn;
            lsum *= scl;
            #pragma unroll
            for (int gg = 0; gg < 4; ++gg)
                #pragma unroll
                for (int r2 = 0; r2 < 4; ++r2) {
                    float sc = __shfl(scl, gg * 8 + 4 * hi + r2);
                    o0[gg * 4 + r2] *= sc;
                    o1[gg * 4 + r2] *= sc;
                }
        }
        #pragma unroll
        for (int r = 0; r < 16; ++r) {
            sa0[r] = exp2f(sa0[r] - mrun);
            sa1[r] = exp2f(sa1[r] - mrun);
        }
        float sm[8];
        #pragma unroll
        for (int r = 0; r < 8; ++r)
            sm[r] = (sa0[r] + sa0[r + 8]) + (sa1[r] + sa1[r + 8]);
        lsum += ((sm[0] + sm[1]) + (sm[2] + sm[3])) + ((sm[4] + sm[5]) + (sm[6] + sm[7]));

        unsigned pw0[8], pw1[8];
        #pragma unroll
        for (int gg = 0; gg < 4; ++gg)
            #pragma unroll
            for (int hh = 0; hh < 2; ++hh) {
                asm("v_cvt_pk_bf16_f32 %0, %1, %2"
                    : "=v"(pw0[gg * 2 + hh]) : "v"(sa0[4 * gg + 2 * hh]), "v"(sa0[4 * gg + 2 * hh + 1]));
                asm("v_cvt_pk_bf16_f32 %0, %1, %2"
                    : "=v"(pw1[gg * 2 + hh]) : "v"(sa1[4 * gg + 2 * hh]), "v"(sa1[4 * gg + 2 * hh + 1]));
            }

        short8 pf[4];
        #pragma unroll
        for (int ks = 0; ks < 4; ++ks) {
            const int g0 = (2 * ks) & 3, g1 = (2 * ks + 1) & 3;
            unsigned p0, q0c, p1, q1c;
            if (ks < 2) { p0 = pw0[g0 * 2]; p1 = pw0[g0 * 2 + 1];
                          q0c = pw0[g1 * 2]; q1c = pw0[g1 * 2 + 1]; }
            else        { p0 = pw1[g0 * 2]; p1 = pw1[g0 * 2 + 1];
                          q0c = pw1[g1 * 2]; q1c = pw1[g1 * 2 + 1]; }
            plswap_u(p0, q0c);
            plswap_u(p1, q1c);
            union { unsigned u[4]; short8 v; } uu;
            uu.u[0] = p0;
            uu.u[1] = p1;
            uu.u[2] = q0c;
            uu.u[3] = q1c;
            pf[ks] = uu.v;
        }

        __builtin_amdgcn_s_setprio(1);
        #pragma unroll
        for (int ks = 0; ks < 4; ++ks) {
            o0 = __builtin_amdgcn_mfma_f32_32x32x16_bf16(pf[ks], vf0[ks], o0, 0, 0, 0);
            o1 = __builtin_amdgcn_mfma_f32_32x32x16_bf16(pf[ks], vf1[ks], o1, 0, 0, 0);
        }
        __builtin_amdgcn_s_setprio(0);
    }

    lsum = plswap_sum(lsum);
    float linv = 1.0f / lsum;
    #pragma unroll
    for (int gg = 0; gg < 4; ++gg)
        #pragma unroll
        for (int r2 = 0; r2 < 4; ++r2) {
            int row = gg * 8 + 4 * hi + r2;
            float li = __shfl(linv, row);
            size_t ybase = rowbase + (size_t)(qw0 + row) * C_EMB;
            Y[ybase + ql]      = f2bf(o0[gg * 4 + r2] * li);
            Y[ybase + 32 + ql] = f2bf(o1[gg * 4 + r2] * li);
        }
}

// ---------------- launcher ----------------
extern "C" void kernel_launch(void* const* d_in, const int* in_sizes, int n_in,
                              void* d_out, int out_size, void* d_ws, size_t ws_size,
                              hipStream_t stream) {
    const float* x  = (const float*)d_in[0];
    const float* Wk = (const float*)d_in[1];
    const float* bk = (const float*)d_in[2];
    const float* Wq = (const float*)d_in[3];
    const float* bq = (const float*)d_in[4];
    const float* Wv = (const float*)d_in[5];
    const float* bv = (const float*)d_in[6];
    const float* Wp = (const float*)d_in[7];
    const float* bp = (const float*)d_in[8];

    const size_t SX = (size_t)8192 * 1024;
    const size_t SW = (size_t)1024 * 1024;

    char* ws = (char*)d_ws;
    unsigned short* xb   = (unsigned short*)ws; ws += SX * 2;
    unsigned short* Wqkv = (unsigned short*)ws; ws += 3 * SW * 2;
    unsigned short* Wpb  = (unsigned short*)ws; ws += SW * 2;
    unsigned short* qb   = (unsigned short*)ws; ws += SX * 2;
    unsigned short* kb   = (unsigned short*)ws; ws += SX * 2;
    unsigned short* vtb  = (unsigned short*)ws; ws += SX * 2;
    unsigned short* yb   = (unsigned short*)ws; ws += SX * 2;

    cvt_all<<<dim3(12288), 256, 0, stream>>>(x, Wq, Wk, Wv, Wp, xb, Wqkv, Wpb);

    gemm_qkv8<<<dim3(12, 32), 512, 0, stream>>>(xb, Wqkv, bq, bk, bv, qb, kb, vtb);

    attn_fwd18<<<dim3(1024), 256, 0, stream>>>(qb, kb, vtb, yb);

    gemm_proj<<<dim3(8, 64), 256, 0, stream>>>(yb, Wpb, bp, (float*)d_out, 8192, 1024, 1024);
}

// Round 19
// 193.417 us; speedup vs baseline: 1.1091x; 1.0181x over previous
//
#include <hip/hip_runtime.h>

typedef __attribute__((ext_vector_type(8))) short short8;
typedef __attribute__((ext_vector_type(4))) float f32x4;
typedef __attribute__((ext_vector_type(16))) float f32x16;
typedef __attribute__((ext_vector_type(4))) unsigned short u16x4;
typedef __attribute__((ext_vector_type(4))) float float4v;

#define AS1 __attribute__((address_space(1)))
#define AS3 __attribute__((address_space(3)))

#define T_SEQ 2048
#define C_EMB 1024
#define NHEAD 16
#define NB    4
#define SCL_Q 0.18033688f   // 0.125 * log2(e)

__device__ __forceinline__ unsigned short f2bf(float f) {
    union { float f; unsigned u; } cv; cv.f = f;
    unsigned u = cv.u;
    unsigned r = (u + 0x7FFFu + ((u >> 16) & 1u)) >> 16;
    return (unsigned short)r;
}

__device__ __forceinline__ void async_load16(const void* g, void* l) {
    __builtin_amdgcn_global_load_lds((const AS1 unsigned*)g, (AS3 unsigned*)l, 16, 0, 0);
}

// permlane32_swap builtin (R12-proven)
__device__ __forceinline__ void plswap_u(unsigned &a, unsigned &b) {
    auto r = __builtin_amdgcn_permlane32_swap(a, b, false, false);
    a = r[0]; b = r[1];
}
__device__ __forceinline__ float plswap_max(float t) {
    union { float f; unsigned u; } c; c.f = t;
    auto r = __builtin_amdgcn_permlane32_swap(c.u, c.u, false, false);
    union { unsigned u; float f; } x0, x1; x0.u = r[0]; x1.u = r[1];
    return fmaxf(x0.f, x1.f);
}
__device__ __forceinline__ float plswap_sum(float t) {
    union { float f; unsigned u; } c; c.f = t;
    auto r = __builtin_amdgcn_permlane32_swap(c.u, c.u, false, false);
    union { unsigned u; float f; } x0, x1; x0.u = r[0]; x1.u = r[1];
    return x0.f + x1.f;
}

// ---------------- fused f32 -> bf16 convert (one launch) ----------------
__global__ void cvt_all(const float* __restrict__ x,
                        const float* __restrict__ wq, const float* __restrict__ wk,
                        const float* __restrict__ wv, const float* __restrict__ wp,
                        unsigned short* __restrict__ xb,
                        unsigned short* __restrict__ wqkv,
                        unsigned short* __restrict__ wpb) {
    const int blk = blockIdx.x;
    const float* src; unsigned short* dst; int idx;
    if (blk < 8192) {
        src = x; dst = xb; idx = blk * 256 + threadIdx.x;
    } else {
        int wsel = (blk - 8192) >> 10;
        idx = ((blk - 8192) & 1023) * 256 + threadIdx.x;
        src = (wsel == 0) ? wq : (wsel == 1) ? wk : (wsel == 2) ? wv : wp;
        dst = (wsel == 3) ? wpb : wqkv + (size_t)wsel * 1048576;
    }
    float4v v = ((const float4v*)src)[idx];
    u16x4 o;
    o[0] = f2bf(v[0]); o[1] = f2bf(v[1]); o[2] = f2bf(v[2]); o[3] = f2bf(v[3]);
    ((u16x4*)dst)[idx] = o;
}

// ---------------- fused QKV GEMM (m97 128-tile, 747 TF proven): [8192,1024]x[3072,1024]^T ----------------
__global__ void gemm_qkv(const unsigned short* __restrict__ A,
                         const unsigned short* __restrict__ W,
                         const float* __restrict__ bq,
                         const float* __restrict__ bk,
                         const float* __restrict__ bv,
                         unsigned short* __restrict__ Qo,
                         unsigned short* __restrict__ Ko,
                         unsigned short* __restrict__ Vt) {
    __shared__ __align__(16) unsigned short As[128 * 32];
    __shared__ __align__(16) unsigned short Bs[128 * 32];
    const int tid  = threadIdx.x;
    const int wid  = tid >> 6;
    const int lane = tid & 63;
    const int lg = lane >> 4, lr = lane & 15;
    const int wr = wid >> 1, wc = wid & 1;
    const int n0 = blockIdx.x * 128;
    const int m0 = blockIdx.y * 128;
    const int K = 1024;

    f32x4 acc[4][4] = {};

    for (int kt = 0; kt < K; kt += 32) {
        #pragma unroll
        for (int r = 0; r < 2; ++r) {
            int cb = r * 4 + wid;
            int chunk = cb * 64 + lane;
            int row = chunk >> 2;
            int col = (chunk & 3) * 8;
            async_load16(&A[(size_t)(m0 + row) * K + kt + col], (char*)As + cb * 1024);
            async_load16(&W[(size_t)(n0 + row) * K + kt + col], (char*)Bs + cb * 1024);
        }
        __syncthreads();
        short8 af[4], bfr[4];
        #pragma unroll
        for (int m = 0; m < 4; ++m)
            af[m] = *(const short8*)&As[(wr * 64 + m * 16 + lr) * 32 + lg * 8];
        #pragma unroll
        for (int n = 0; n < 4; ++n)
            bfr[n] = *(const short8*)&Bs[(wc * 64 + n * 16 + lr) * 32 + lg * 8];
        #pragma unroll
        for (int m = 0; m < 4; ++m)
            #pragma unroll
            for (int n = 0; n < 4; ++n)
                acc[m][n] = __builtin_amdgcn_mfma_f32_16x16x32_bf16(af[m], bfr[n], acc[m][n], 0, 0, 0);
        __syncthreads();
    }

    const int sel = n0 >> 10;                       // 0=Q 1=K 2=V (block-uniform)
    const int nl0 = n0 & 1023;
    const float* bias = (sel == 0) ? bq : (sel == 1) ? bk : bv;
    const float scale = (sel == 0) ? SCL_Q : 1.0f;

    #pragma unroll
    for (int n = 0; n < 4; ++n) {
        int cc = nl0 + wc * 64 + n * 16 + lr;
        float bvv = bias[cc];
        #pragma unroll
        for (int m = 0; m < 4; ++m) {
            int rr0 = m0 + wr * 64 + m * 16 + lg * 4;
            u16x4 pk;
            #pragma unroll
            for (int r = 0; r < 4; ++r)
                pk[r] = f2bf((acc[m][n][r] + bvv) * scale);
            if (sel == 2) {
                size_t idx = ((size_t)(rr0 >> 11) * 1024 + cc) * 2048 + (rr0 & 2047);
                *(u16x4*)&Vt[idx] = pk;
            } else {
                unsigned short* out = (sel == 0) ? Qo : Ko;
                #pragma unroll
                for (int r = 0; r < 4; ++r)
                    out[(size_t)(rr0 + r) * 1024 + cc] = pk[r];
            }
        }
    }
}

// ---------------- proj GEMM (m97 128-tile): C = A*B^T + bias (f32 out) ----------------
__global__ void gemm_proj(const unsigned short* __restrict__ A,
                          const unsigned short* __restrict__ B,
                          const float* __restrict__ bias,
                          float* __restrict__ Cout,
                          int M, int N, int K) {
    __shared__ __align__(16) unsigned short As[128 * 32];
    __shared__ __align__(16) unsigned short Bs[128 * 32];
    const int tid  = threadIdx.x;
    const int wid  = tid >> 6;
    const int lane = tid & 63;
    const int lg = lane >> 4, lr = lane & 15;
    const int wr = wid >> 1, wc = wid & 1;
    const int n0 = blockIdx.x * 128;
    const int m0 = blockIdx.y * 128;

    f32x4 acc[4][4] = {};

    for (int kt = 0; kt < K; kt += 32) {
        #pragma unroll
        for (int r = 0; r < 2; ++r) {
            int cb = r * 4 + wid;
            int chunk = cb * 64 + lane;
            int row = chunk >> 2;
            int col = (chunk & 3) * 8;
            async_load16(&A[(size_t)(m0 + row) * K + kt + col], (char*)As + cb * 1024);
            async_load16(&B[(size_t)(n0 + row) * K + kt + col], (char*)Bs + cb * 1024);
        }
        __syncthreads();
        short8 af[4], bfr[4];
        #pragma unroll
        for (int m = 0; m < 4; ++m)
            af[m] = *(const short8*)&As[(wr * 64 + m * 16 + lr) * 32 + lg * 8];
        #pragma unroll
        for (int n = 0; n < 4; ++n)
            bfr[n] = *(const short8*)&Bs[(wc * 64 + n * 16 + lr) * 32 + lg * 8];
        #pragma unroll
        for (int m = 0; m < 4; ++m)
            #pragma unroll
            for (int n = 0; n < 4; ++n)
                acc[m][n] = __builtin_amdgcn_mfma_f32_16x16x32_bf16(af[m], bfr[n], acc[m][n], 0, 0, 0);
        __syncthreads();
    }

    #pragma unroll
    for (int n = 0; n < 4; ++n) {
        int cc = n0 + wc * 64 + n * 16 + lr;
        float bvv = bias[cc];
        #pragma unroll
        for (int m = 0; m < 4; ++m) {
            int rr0 = m0 + wr * 64 + m * 16 + lg * 4;
            #pragma unroll
            for (int r = 0; r < 4; ++r)
                Cout[(size_t)(rr0 + r) * N + cc] = acc[m][n][r] + bvv;
        }
    }
}

// ---------------- flash attention (R14-proven best: 4-wave 32x32, ~90us) ----------------
__global__ __launch_bounds__(256, 2) void attn_fwd19(const unsigned short* __restrict__ Q,
                                                     const unsigned short* __restrict__ Kg,
                                                     const unsigned short* __restrict__ Vt,
                                                     unsigned short* __restrict__ Y) {
    __shared__ __align__(16) unsigned short Ks[2][64 * 64];

    const int bid = blockIdx.x;
    const int xcd = bid & 7;
    const int s   = bid >> 3;
    const int grp = 15 - (s >> 3);
    const int bh  = (s & 7) * 8 + xcd;
    const int h   = bh & 15;
    const int b   = bh >> 4;

    const int tid  = threadIdx.x;
    const int w    = tid >> 6;
    const int lane = tid & 63;
    const int ql = lane & 31, hi = lane >> 5;

    const size_t rowbase = ((size_t)b * T_SEQ) * C_EMB + (size_t)h * 64;
    const size_t vtbase  = ((size_t)b * 1024 + (size_t)h * 64) * T_SEQ;

    const int srow = lane >> 3;
    const int scol = ((lane & 7) ^ srow) * 8;

    const int q0  = grp * 128;
    const int qw0 = q0 + w * 32;
    const int ntiles = 2 * grp + 2;

    short8 qf[4];
    #pragma unroll
    for (int ds = 0; ds < 4; ++ds)
        qf[ds] = *(const short8*)&Q[rowbase + (size_t)(qw0 + ql) * C_EMB + ds * 16 + hi * 8];

    f32x16 o0 = {}, o1 = {};
    float mrun = -1e30f, lsum = 0.0f;

    #pragma unroll
    for (int i = 0; i < 2; ++i) {
        int cb = w * 2 + i;
        async_load16(&Kg[rowbase + (size_t)(cb * 8 + srow) * C_EMB + scol],
                     (char*)Ks[0] + cb * 1024);
    }

    #pragma unroll 1
    for (int t = 0; t < ntiles; ++t) {
        const int kv0 = t * 64;
        const int cur = t & 1, nxt = cur ^ 1;
        __syncthreads();

        const bool active = (kv0 <= qw0 + 31);

        short8 vf0[4], vf1[4];
        if (active) {
            #pragma unroll
            for (int ks = 0; ks < 4; ++ks) {
                vf0[ks] = *(const short8*)&Vt[vtbase + (size_t)ql * T_SEQ + kv0 + ks * 16 + hi * 8];
                vf1[ks] = *(const short8*)&Vt[vtbase + (size_t)(32 + ql) * T_SEQ + kv0 + ks * 16 + hi * 8];
            }
        }
        if (t + 1 < ntiles) {
            #pragma unroll
            for (int i = 0; i < 2; ++i) {
                int cb = w * 2 + i;
                async_load16(&Kg[rowbase + (size_t)(kv0 + 64 + cb * 8 + srow) * C_EMB + scol],
                             (char*)Ks[nxt] + cb * 1024);
            }
        }
        if (!active) continue;

        f32x16 sa0 = {}, sa1 = {};
        __builtin_amdgcn_s_setprio(1);
        #pragma unroll
        for (int ds = 0; ds < 4; ++ds) {
            short8 a0 = *(const short8*)((const char*)Ks[cur] + (ql) * 128 +
                                         ((ds * 32 + hi * 16) ^ ((ql & 7) << 4)));
            short8 a1 = *(const short8*)((const char*)Ks[cur] + (32 + ql) * 128 +
                                         ((ds * 32 + hi * 16) ^ ((ql & 7) << 4)));
            sa0 = __builtin_amdgcn_mfma_f32_32x32x16_bf16(a0, qf[ds], sa0, 0, 0, 0);
            sa1 = __builtin_amdgcn_mfma_f32_32x32x16_bf16(a1, qf[ds], sa1, 0, 0, 0);
        }
        __builtin_amdgcn_s_setprio(0);

        if (kv0 + 63 > qw0) {
            const int qi = qw0 + ql;
            #pragma unroll
            for (int r = 0; r < 16; ++r) {
                int kl = (r & 3) + 8 * (r >> 2) + 4 * hi;
                if (kv0 + kl > qi)      sa0[r] = -1e30f;
                if (kv0 + 32 + kl > qi) sa1[r] = -1e30f;
            }
        }

        float mx[8];
        #pragma unroll
        for (int r = 0; r < 8; ++r)
            mx[r] = fmaxf(fmaxf(sa0[r], sa0[r + 8]), fmaxf(sa1[r], sa1[r + 8]));
        mx[0] = fmaxf(mx[0], mx[4]); mx[1] = fmaxf(mx[1], mx[5]);
        mx[2] = fmaxf(mx[2], mx[6]); mx[3] = fmaxf(mx[3], mx[7]);
        float tmax = fmaxf(fmaxf(mx[0], mx[1]), fmaxf(mx[2], mx[3]));
        tmax = plswap_max(tmax);
        if (!__all(tmax <= mrun + 8.0f)) {
            float mn  = fmaxf(mrun, tmax);
            float scl = exp2f(mrun - mn);
            mrun = mn;
            lsum *= scl;
            #pragma unroll
            for (int gg = 0; gg < 4; ++gg)
                #pragma unroll
                for (int r2 = 0; r2 < 4; ++r2) {
                    float sc = __shfl(scl, gg * 8 + 4 * hi + r2);
                    o0[gg * 4 + r2] *= sc;
                    o1[gg * 4 + r2] *= sc;
                }
        }
        #pragma unroll
        for (int r = 0; r < 16; ++r) {
            sa0[r] = exp2f(sa0[r] - mrun);
            sa1[r] = exp2f(sa1[r] - mrun);
        }
        float sm[8];
        #pragma unroll
        for (int r = 0; r < 8; ++r)
            sm[r] = (sa0[r] + sa0[r + 8]) + (sa1[r] + sa1[r + 8]);
        lsum += ((sm[0] + sm[1]) + (sm[2] + sm[3])) + ((sm[4] + sm[5]) + (sm[6] + sm[7]));

        unsigned pw0[8], pw1[8];
        #pragma unroll
        for (int gg = 0; gg < 4; ++gg)
            #pragma unroll
            for (int hh = 0; hh < 2; ++hh) {
                asm("v_cvt_pk_bf16_f32 %0, %1, %2"
                    : "=v"(pw0[gg * 2 + hh]) : "v"(sa0[4 * gg + 2 * hh]), "v"(sa0[4 * gg + 2 * hh + 1]));
                asm("v_cvt_pk_bf16_f32 %0, %1, %2"
                    : "=v"(pw1[gg * 2 + hh]) : "v"(sa1[4 * gg + 2 * hh]), "v"(sa1[4 * gg + 2 * hh + 1]));
            }

        short8 pf[4];
        #pragma unroll
        for (int ks = 0; ks < 4; ++ks) {
            const int g0 = (2 * ks) & 3, g1 = (2 * ks + 1) & 3;
            unsigned p0, q0c, p1, q1c;
            if (ks < 2) { p0 = pw0[g0 * 2]; p1 = pw0[g0 * 2 + 1];
                          q0c = pw0[g1 * 2]; q1c = pw0[g1 * 2 + 1]; }
            else        { p0 = pw1[g0 * 2]; p1 = pw1[g0 * 2 + 1];
                          q0c = pw1[g1 * 2]; q1c = pw1[g1 * 2 + 1]; }
            plswap_u(p0, q0c);
            plswap_u(p1, q1c);
            union { unsigned u[4]; short8 v; } uu;
            uu.u[0] = p0;
            uu.u[1] = p1;
            uu.u[2] = q0c;
            uu.u[3] = q1c;
            pf[ks] = uu.v;
        }

        __builtin_amdgcn_s_setprio(1);
        #pragma unroll
        for (int ks = 0; ks < 4; ++ks) {
            o0 = __builtin_amdgcn_mfma_f32_32x32x16_bf16(pf[ks], vf0[ks], o0, 0, 0, 0);
            o1 = __builtin_amdgcn_mfma_f32_32x32x16_bf16(pf[ks], vf1[ks], o1, 0, 0, 0);
        }
        __builtin_amdgcn_s_setprio(0);
    }

    lsum = plswap_sum(lsum);
    float linv = 1.0f / lsum;
    #pragma unroll
    for (int gg = 0; gg < 4; ++gg)
        #pragma unroll
        for (int r2 = 0; r2 < 4; ++r2) {
            int row = gg * 8 + 4 * hi + r2;
            float li = __shfl(linv, row);
            size_t ybase = rowbase + (size_t)(qw0 + row) * C_EMB;
            Y[ybase + ql]      = f2bf(o0[gg * 4 + r2] * li);
            Y[ybase + 32 + ql] = f2bf(o1[gg * 4 + r2] * li);
        }
}

// ---------------- launcher ----------------
extern "C" void kernel_launch(void* const* d_in, const int* in_sizes, int n_in,
                              void* d_out, int out_size, void* d_ws, size_t ws_size,
                              hipStream_t stream) {
    const float* x  = (const float*)d_in[0];
    const float* Wk = (const float*)d_in[1];
    const float* bk = (const float*)d_in[2];
    const float* Wq = (const float*)d_in[3];
    const float* bq = (const float*)d_in[4];
    const float* Wv = (const float*)d_in[5];
    const float* bv = (const float*)d_in[6];
    const float* Wp = (const float*)d_in[7];
    const float* bp = (const float*)d_in[8];

    const size_t SX = (size_t)8192 * 1024;
    const size_t SW = (size_t)1024 * 1024;

    char* ws = (char*)d_ws;
    unsigned short* xb   = (unsigned short*)ws; ws += SX * 2;
    unsigned short* Wqkv = (unsigned short*)ws; ws += 3 * SW * 2;  // [Wq;Wk;Wv] rows
    unsigned short* Wpb  = (unsigned short*)ws; ws += SW * 2;
    unsigned short* qb   = (unsigned short*)ws; ws += SX * 2;
    unsigned short* kb   = (unsigned short*)ws; ws += SX * 2;
    unsigned short* vtb  = (unsigned short*)ws; ws += SX * 2;  // V^T per head [b][h][d][t]
    unsigned short* yb   = (unsigned short*)ws; ws += SX * 2;

    cvt_all<<<dim3(12288), 256, 0, stream>>>(x, Wq, Wk, Wv, Wp, xb, Wqkv, Wpb);

    gemm_qkv<<<dim3(24, 64), 256, 0, stream>>>(xb, Wqkv, bq, bk, bv, qb, kb, vtb);

    attn_fwd19<<<dim3(1024), 256, 0, stream>>>(qb, kb, vtb, yb);

    gemm_proj<<<dim3(8, 64), 256, 0, stream>>>(yb, Wpb, bp, (float*)d_out, 8192, 1024, 1024);
}

// Round 20
// 188.870 us; speedup vs baseline: 1.1358x; 1.0241x over previous
//
#include <hip/hip_runtime.h>

typedef __attribute__((ext_vector_type(8))) short short8;
typedef __attribute__((ext_vector_type(4))) float f32x4;
typedef __attribute__((ext_vector_type(16))) float f32x16;
typedef __attribute__((ext_vector_type(4))) unsigned short u16x4;
typedef __attribute__((ext_vector_type(4))) float float4v;

#define AS1 __attribute__((address_space(1)))
#define AS3 __attribute__((address_space(3)))

#define T_SEQ 2048
#define C_EMB 1024
#define NHEAD 16
#define NB    4
#define SCL_Q 0.18033688f   // 0.125 * log2(e)

__device__ __forceinline__ unsigned short f2bf(float f) {
    union { float f; unsigned u; } cv; cv.f = f;
    unsigned u = cv.u;
    unsigned r = (u + 0x7FFFu + ((u >> 16) & 1u)) >> 16;
    return (unsigned short)r;
}

__device__ __forceinline__ void async_load16(const void* g, void* l) {
    __builtin_amdgcn_global_load_lds((const AS1 unsigned*)g, (AS3 unsigned*)l, 16, 0, 0);
}

// permlane32_swap builtin (R12-proven)
__device__ __forceinline__ void plswap_u(unsigned &a, unsigned &b) {
    auto r = __builtin_amdgcn_permlane32_swap(a, b, false, false);
    a = r[0]; b = r[1];
}
__device__ __forceinline__ float plswap_max(float t) {
    union { float f; unsigned u; } c; c.f = t;
    auto r = __builtin_amdgcn_permlane32_swap(c.u, c.u, false, false);
    union { unsigned u; float f; } x0, x1; x0.u = r[0]; x1.u = r[1];
    return fmaxf(x0.f, x1.f);
}
__device__ __forceinline__ float plswap_sum(float t) {
    union { float f; unsigned u; } c; c.f = t;
    auto r = __builtin_amdgcn_permlane32_swap(c.u, c.u, false, false);
    union { unsigned u; float f; } x0, x1; x0.u = r[0]; x1.u = r[1];
    return x0.f + x1.f;
}

// ---------------- fused f32 -> bf16 convert (one launch) ----------------
__global__ void cvt_all(const float* __restrict__ x,
                        const float* __restrict__ wq, const float* __restrict__ wk,
                        const float* __restrict__ wv, const float* __restrict__ wp,
                        unsigned short* __restrict__ xb,
                        unsigned short* __restrict__ wqkv,
                        unsigned short* __restrict__ wpb) {
    const int blk = blockIdx.x;
    const float* src; unsigned short* dst; int idx;
    if (blk < 8192) {
        src = x; dst = xb; idx = blk * 256 + threadIdx.x;
    } else {
        int wsel = (blk - 8192) >> 10;
        idx = ((blk - 8192) & 1023) * 256 + threadIdx.x;
        src = (wsel == 0) ? wq : (wsel == 1) ? wk : (wsel == 2) ? wv : wp;
        dst = (wsel == 3) ? wpb : wqkv + (size_t)wsel * 1048576;
    }
    float4v v = ((const float4v*)src)[idx];
    u16x4 o;
    o[0] = f2bf(v[0]); o[1] = f2bf(v[1]); o[2] = f2bf(v[2]); o[3] = f2bf(v[3]);
    ((u16x4*)dst)[idx] = o;
}

// ---------------- fused QKV GEMM, m97 skeleton with BK=64 + XOR swizzle ----------------
// 128x128 tile, BK=64 (16 K-iters -> half the barrier-drain convoys of BK=32).
// LDS 32KB single-buffered; both-sides granule swizzle (R16-18: conflicts==0,
// numerically verified). Inner: per kk { 8 ds_read_b128, 16 MFMA } keeps live
// VGPR at m97 levels.
__global__ void gemm_qkv(const unsigned short* __restrict__ A,
                         const unsigned short* __restrict__ W,
                         const float* __restrict__ bq,
                         const float* __restrict__ bk,
                         const float* __restrict__ bv,
                         unsigned short* __restrict__ Qo,
                         unsigned short* __restrict__ Ko,
                         unsigned short* __restrict__ Vt) {
    __shared__ __align__(16) unsigned short As[128 * 64];   // 16 KB
    __shared__ __align__(16) unsigned short Bs[128 * 64];   // 16 KB
    const int tid  = threadIdx.x;
    const int wid  = tid >> 6;
    const int lane = tid & 63;
    const int lg = lane >> 4, lr = lane & 15;
    const int wr = wid >> 1, wc = wid & 1;
    const int n0 = blockIdx.x * 128;
    const int m0 = blockIdx.y * 128;
    const int K = 1024;

    // staging: chunk = 8 rows x 64 cols (1KB). lane: row lane>>3, granule lane&7.
    const int srw = lane >> 3;                       // 0..7
    const int sgE = (((lane & 7) ^ srw)) * 8;        // swizzled global col elems
    const int sw  = (lr & 7) << 4;                   // read-side XOR (bytes)

    f32x4 acc[4][4] = {};

    for (int kt = 0; kt < K; kt += 64) {
        #pragma unroll
        for (int i = 0; i < 4; ++i) {
            int cb = wid * 4 + i;                    // 0..15
            async_load16(&A[(size_t)(m0 + cb * 8 + srw) * K + kt + sgE],
                         (char*)As + cb * 1024 + lane * 16);
            async_load16(&W[(size_t)(n0 + cb * 8 + srw) * K + kt + sgE],
                         (char*)Bs + cb * 1024 + lane * 16);
        }
        __syncthreads();
        #pragma unroll
        for (int kk = 0; kk < 2; ++kk) {
            short8 af[4], bfr[4];
            #pragma unroll
            for (int m = 0; m < 4; ++m) {
                int row = wr * 64 + m * 16 + lr;
                af[m] = *(const short8*)((const char*)As + row * 128 +
                                         ((kk * 64 + lg * 16) ^ sw));
            }
            #pragma unroll
            for (int n = 0; n < 4; ++n) {
                int row = wc * 64 + n * 16 + lr;
                bfr[n] = *(const short8*)((const char*)Bs + row * 128 +
                                          ((kk * 64 + lg * 16) ^ sw));
            }
            #pragma unroll
            for (int m = 0; m < 4; ++m)
                #pragma unroll
                for (int n = 0; n < 4; ++n)
                    acc[m][n] = __builtin_amdgcn_mfma_f32_16x16x32_bf16(af[m], bfr[n], acc[m][n], 0, 0, 0);
        }
        __syncthreads();
    }

    const int sel = n0 >> 10;                        // 0=Q 1=K 2=V (block-uniform)
    const int nl0 = n0 & 1023;
    const float* bias = (sel == 0) ? bq : (sel == 1) ? bk : bv;
    const float scale = (sel == 0) ? SCL_Q : 1.0f;

    #pragma unroll
    for (int n = 0; n < 4; ++n) {
        int cc = nl0 + wc * 64 + n * 16 + lr;
        float bvv = bias[cc];
        #pragma unroll
        for (int m = 0; m < 4; ++m) {
            int rr0 = m0 + wr * 64 + m * 16 + lg * 4;
            u16x4 pk;
            #pragma unroll
            for (int r = 0; r < 4; ++r)
                pk[r] = f2bf((acc[m][n][r] + bvv) * scale);
            if (sel == 2) {
                size_t idx = ((size_t)(rr0 >> 11) * 1024 + cc) * 2048 + (rr0 & 2047);
                *(u16x4*)&Vt[idx] = pk;
            } else {
                unsigned short* out = (sel == 0) ? Qo : Ko;
                #pragma unroll
                for (int r = 0; r < 4; ++r)
                    out[(size_t)(rr0 + r) * 1024 + cc] = pk[r];
            }
        }
    }
}

// ---------------- proj GEMM, m97 skeleton with BK=64 + XOR swizzle (f32 out) ----------------
__global__ void gemm_proj(const unsigned short* __restrict__ A,
                          const unsigned short* __restrict__ B,
                          const float* __restrict__ bias,
                          float* __restrict__ Cout,
                          int M, int N, int K) {
    __shared__ __align__(16) unsigned short As[128 * 64];
    __shared__ __align__(16) unsigned short Bs[128 * 64];
    const int tid  = threadIdx.x;
    const int wid  = tid >> 6;
    const int lane = tid & 63;
    const int lg = lane >> 4, lr = lane & 15;
    const int wr = wid >> 1, wc = wid & 1;
    const int n0 = blockIdx.x * 128;
    const int m0 = blockIdx.y * 128;

    const int srw = lane >> 3;
    const int sgE = (((lane & 7) ^ srw)) * 8;
    const int sw  = (lr & 7) << 4;

    f32x4 acc[4][4] = {};

    for (int kt = 0; kt < K; kt += 64) {
        #pragma unroll
        for (int i = 0; i < 4; ++i) {
            int cb = wid * 4 + i;
            async_load16(&A[(size_t)(m0 + cb * 8 + srw) * K + kt + sgE],
                         (char*)As + cb * 1024 + lane * 16);
            async_load16(&B[(size_t)(n0 + cb * 8 + srw) * K + kt + sgE],
                         (char*)Bs + cb * 1024 + lane * 16);
        }
        __syncthreads();
        #pragma unroll
        for (int kk = 0; kk < 2; ++kk) {
            short8 af[4], bfr[4];
            #pragma unroll
            for (int m = 0; m < 4; ++m) {
                int row = wr * 64 + m * 16 + lr;
                af[m] = *(const short8*)((const char*)As + row * 128 +
                                         ((kk * 64 + lg * 16) ^ sw));
            }
            #pragma unroll
            for (int n = 0; n < 4; ++n) {
                int row = wc * 64 + n * 16 + lr;
                bfr[n] = *(const short8*)((const char*)Bs + row * 128 +
                                          ((kk * 64 + lg * 16) ^ sw));
            }
            #pragma unroll
            for (int m = 0; m < 4; ++m)
                #pragma unroll
                for (int n = 0; n < 4; ++n)
                    acc[m][n] = __builtin_amdgcn_mfma_f32_16x16x32_bf16(af[m], bfr[n], acc[m][n], 0, 0, 0);
        }
        __syncthreads();
    }

    #pragma unroll
    for (int n = 0; n < 4; ++n) {
        int cc = n0 + wc * 64 + n * 16 + lr;
        float bvv = bias[cc];
        #pragma unroll
        for (int m = 0; m < 4; ++m) {
            int rr0 = m0 + wr * 64 + m * 16 + lg * 4;
            #pragma unroll
            for (int r = 0; r < 4; ++r)
                Cout[(size_t)(rr0 + r) * N + cc] = acc[m][n][r] + bvv;
        }
    }
}

// ---------------- flash attention (R14-proven best: 4-wave 32x32, ~90us) ----------------
__global__ __launch_bounds__(256, 2) void attn_fwd20(const unsigned short* __restrict__ Q,
                                                     const unsigned short* __restrict__ Kg,
                                                     const unsigned short* __restrict__ Vt,
                                                     unsigned short* __restrict__ Y) {
    __shared__ __align__(16) unsigned short Ks[2][64 * 64];

    const int bid = blockIdx.x;
    const int xcd = bid & 7;
    const int s   = bid >> 3;
    const int grp = 15 - (s >> 3);
    const int bh  = (s & 7) * 8 + xcd;
    const int h   = bh & 15;
    const int b   = bh >> 4;

    const int tid  = threadIdx.x;
    const int w    = tid >> 6;
    const int lane = tid & 63;
    const int ql = lane & 31, hi = lane >> 5;

    const size_t rowbase = ((size_t)b * T_SEQ) * C_EMB + (size_t)h * 64;
    const size_t vtbase  = ((size_t)b * 1024 + (size_t)h * 64) * T_SEQ;

    const int srow = lane >> 3;
    const int scol = ((lane & 7) ^ srow) * 8;

    const int q0  = grp * 128;
    const int qw0 = q0 + w * 32;
    const int ntiles = 2 * grp + 2;

    short8 qf[4];
    #pragma unroll
    for (int ds = 0; ds < 4; ++ds)
        qf[ds] = *(const short8*)&Q[rowbase + (size_t)(qw0 + ql) * C_EMB + ds * 16 + hi * 8];

    f32x16 o0 = {}, o1 = {};
    float mrun = -1e30f, lsum = 0.0f;

    #pragma unroll
    for (int i = 0; i < 2; ++i) {
        int cb = w * 2 + i;
        async_load16(&Kg[rowbase + (size_t)(cb * 8 + srow) * C_EMB + scol],
                     (char*)Ks[0] + cb * 1024);
    }

    #pragma unroll 1
    for (int t = 0; t < ntiles; ++t) {
        const int kv0 = t * 64;
        const int cur = t & 1, nxt = cur ^ 1;
        __syncthreads();

        const bool active = (kv0 <= qw0 + 31);

        short8 vf0[4], vf1[4];
        if (active) {
            #pragma unroll
            for (int ks = 0; ks < 4; ++ks) {
                vf0[ks] = *(const short8*)&Vt[vtbase + (size_t)ql * T_SEQ + kv0 + ks * 16 + hi * 8];
                vf1[ks] = *(const short8*)&Vt[vtbase + (size_t)(32 + ql) * T_SEQ + kv0 + ks * 16 + hi * 8];
            }
        }
        if (t + 1 < ntiles) {
            #pragma unroll
            for (int i = 0; i < 2; ++i) {
                int cb = w * 2 + i;
                async_load16(&Kg[rowbase + (size_t)(kv0 + 64 + cb * 8 + srow) * C_EMB + scol],
                             (char*)Ks[nxt] + cb * 1024);
            }
        }
        if (!active) continue;

        f32x16 sa0 = {}, sa1 = {};
        __builtin_amdgcn_s_setprio(1);
        #pragma unroll
        for (int ds = 0; ds < 4; ++ds) {
            short8 a0 = *(const short8*)((const char*)Ks[cur] + (ql) * 128 +
                                         ((ds * 32 + hi * 16) ^ ((ql & 7) << 4)));
            short8 a1 = *(const short8*)((const char*)Ks[cur] + (32 + ql) * 128 +
                                         ((ds * 32 + hi * 16) ^ ((ql & 7) << 4)));
            sa0 = __builtin_amdgcn_mfma_f32_32x32x16_bf16(a0, qf[ds], sa0, 0, 0, 0);
            sa1 = __builtin_amdgcn_mfma_f32_32x32x16_bf16(a1, qf[ds], sa1, 0, 0, 0);
        }
        __builtin_amdgcn_s_setprio(0);

        if (kv0 + 63 > qw0) {
            const int qi = qw0 + ql;
            #pragma unroll
            for (int r = 0; r < 16; ++r) {
                int kl = (r & 3) + 8 * (r >> 2) + 4 * hi;
                if (kv0 + kl > qi)      sa0[r] = -1e30f;
                if (kv0 + 32 + kl > qi) sa1[r] = -1e30f;
            }
        }

        float mx[8];
        #pragma unroll
        for (int r = 0; r < 8; ++r)
            mx[r] = fmaxf(fmaxf(sa0[r], sa0[r + 8]), fmaxf(sa1[r], sa1[r + 8]));
        mx[0] = fmaxf(mx[0], mx[4]); mx[1] = fmaxf(mx[1], mx[5]);
        mx[2] = fmaxf(mx[2], mx[6]); mx[3] = fmaxf(mx[3], mx[7]);
        float tmax = fmaxf(fmaxf(mx[0], mx[1]), fmaxf(mx[2], mx[3]));
        tmax = plswap_max(tmax);
        if (!__all(tmax <= mrun + 8.0f)) {
            float mn  = fmaxf(mrun, tmax);
            float scl = exp2f(mrun - mn);
            mrun = mn;
            lsum *= scl;
            #pragma unroll
            for (int gg = 0; gg < 4; ++gg)
                #pragma unroll
                for (int r2 = 0; r2 < 4; ++r2) {
                    float sc = __shfl(scl, gg * 8 + 4 * hi + r2);
                    o0[gg * 4 + r2] *= sc;
                    o1[gg * 4 + r2] *= sc;
                }
        }
        #pragma unroll
        for (int r = 0; r < 16; ++r) {
            sa0[r] = exp2f(sa0[r] - mrun);
            sa1[r] = exp2f(sa1[r] - mrun);
        }
        float sm[8];
        #pragma unroll
        for (int r = 0; r < 8; ++r)
            sm[r] = (sa0[r] + sa0[r + 8]) + (sa1[r] + sa1[r + 8]);
        lsum += ((sm[0] + sm[1]) + (sm[2] + sm[3])) + ((sm[4] + sm[5]) + (sm[6] + sm[7]));

        unsigned pw0[8], pw1[8];
        #pragma unroll
        for (int gg = 0; gg < 4; ++gg)
            #pragma unroll
            for (int hh = 0; hh < 2; ++hh) {
                asm("v_cvt_pk_bf16_f32 %0, %1, %2"
                    : "=v"(pw0[gg * 2 + hh]) : "v"(sa0[4 * gg + 2 * hh]), "v"(sa0[4 * gg + 2 * hh + 1]));
                asm("v_cvt_pk_bf16_f32 %0, %1, %2"
                    : "=v"(pw1[gg * 2 + hh]) : "v"(sa1[4 * gg + 2 * hh]), "v"(sa1[4 * gg + 2 * hh + 1]));
            }

        short8 pf[4];
        #pragma unroll
        for (int ks = 0; ks < 4; ++ks) {
            const int g0 = (2 * ks) & 3, g1 = (2 * ks + 1) & 3;
            unsigned p0, q0c, p1, q1c;
            if (ks < 2) { p0 = pw0[g0 * 2]; p1 = pw0[g0 * 2 + 1];
                          q0c = pw0[g1 * 2]; q1c = pw0[g1 * 2 + 1]; }
            else        { p0 = pw1[g0 * 2]; p1 = pw1[g0 * 2 + 1];
                          q0c = pw1[g1 * 2]; q1c = pw1[g1 * 2 + 1]; }
            plswap_u(p0, q0c);
            plswap_u(p1, q1c);
            union { unsigned u[4]; short8 v; } uu;
            uu.u[0] = p0;
            uu.u[1] = p1;
            uu.u[2] = q0c;
            uu.u[3] = q1c;
            pf[ks] = uu.v;
        }

        __builtin_amdgcn_s_setprio(1);
        #pragma unroll
        for (int ks = 0; ks < 4; ++ks) {
            o0 = __builtin_amdgcn_mfma_f32_32x32x16_bf16(pf[ks], vf0[ks], o0, 0, 0, 0);
            o1 = __builtin_amdgcn_mfma_f32_32x32x16_bf16(pf[ks], vf1[ks], o1, 0, 0, 0);
        }
        __builtin_amdgcn_s_setprio(0);
    }

    lsum = plswap_sum(lsum);
    float linv = 1.0f / lsum;
    #pragma unroll
    for (int gg = 0; gg < 4; ++gg)
        #pragma unroll
        for (int r2 = 0; r2 < 4; ++r2) {
            int row = gg * 8 + 4 * hi + r2;
            float li = __shfl(linv, row);
            size_t ybase = rowbase + (size_t)(qw0 + row) * C_EMB;
            Y[ybase + ql]      = f2bf(o0[gg * 4 + r2] * li);
            Y[ybase + 32 + ql] = f2bf(o1[gg * 4 + r2] * li);
        }
}

// ---------------- launcher ----------------
extern "C" void kernel_launch(void* const* d_in, const int* in_sizes, int n_in,
                              void* d_out, int out_size, void* d_ws, size_t ws_size,
                              hipStream_t stream) {
    const float* x  = (const float*)d_in[0];
    const float* Wk = (const float*)d_in[1];
    const float* bk = (const float*)d_in[2];
    const float* Wq = (const float*)d_in[3];
    const float* bq = (const float*)d_in[4];
    const float* Wv = (const float*)d_in[5];
    const float* bv = (const float*)d_in[6];
    const float* Wp = (const float*)d_in[7];
    const float* bp = (const float*)d_in[8];

    const size_t SX = (size_t)8192 * 1024;
    const size_t SW = (size_t)1024 * 1024;

    char* ws = (char*)d_ws;
    unsigned short* xb   = (unsigned short*)ws; ws += SX * 2;
    unsigned short* Wqkv = (unsigned short*)ws; ws += 3 * SW * 2;  // [Wq;Wk;Wv] rows
    unsigned short* Wpb  = (unsigned short*)ws; ws += SW * 2;
    unsigned short* qb   = (unsigned short*)ws; ws += SX * 2;
    unsigned short* kb   = (unsigned short*)ws; ws += SX * 2;
    unsigned short* vtb  = (unsigned short*)ws; ws += SX * 2;  // V^T per head [b][h][d][t]
    unsigned short* yb   = (unsigned short*)ws; ws += SX * 2;

    cvt_all<<<dim3(12288), 256, 0, stream>>>(x, Wq, Wk, Wv, Wp, xb, Wqkv, Wpb);

    gemm_qkv<<<dim3(24, 64), 256, 0, stream>>>(xb, Wqkv, bq, bk, bv, qb, kb, vtb);

    attn_fwd20<<<dim3(1024), 256, 0, stream>>>(qb, kb, vtb, yb);

    gemm_proj<<<dim3(8, 64), 256, 0, stream>>>(yb, Wpb, bp, (float*)d_out, 8192, 1024, 1024);
}